// Round 6
// baseline (526.811 us; speedup 1.0000x reference)
//
#include <hip/hip_runtime.h>

typedef __bf16 bf16x4 __attribute__((ext_vector_type(4)));
typedef __bf16 bf16x8 __attribute__((ext_vector_type(8)));
typedef float  f32x4  __attribute__((ext_vector_type(4)));

#define HWSZ 4096
#define CCH  256
#define LOG2E 1.44269504088896340736f

enum { M_CONV = 1, M_G1 = 4, M_FUSE = 5 };

__device__ __forceinline__ float exp2_fast(float x) {
#if __has_builtin(__builtin_amdgcn_exp2f)
  return __builtin_amdgcn_exp2f(x);
#else
  return exp2f(x);
#endif
}

// stage 16B per lane into LDS; lane's data lands at lds_base + lane*16B
__device__ __forceinline__ void stage16(const __bf16* g, __bf16* ldsBase) {
#if __has_builtin(__builtin_amdgcn_global_load_lds)
  __builtin_amdgcn_global_load_lds(
      (const __attribute__((address_space(1))) void*)g,
      (__attribute__((address_space(3))) void*)ldsBase, 16, 0, 0);
#else
  int lane = threadIdx.x & 63;
  *(bf16x8*)(ldsBase + lane * 8) = *(const bf16x8*)g;
#endif
}

// ---------------------------------------------------------------------------
// Generic 128x128x32 bf16 MFMA GEMM, C = A * B^T, A[M,K], B[N,K] K-contiguous.
// 256 threads = 4 waves 2x2, wave 64x64 (4x4 16x16x32 MFMA tiles).
// M_CONV : merged conv3x3 GEMM. by<8: A=AL (M=1024, Fl imgs), else A=A2=AV.
// M_G1   : 1x1 conv + bias + residual; blockIdx.z = br*2+z; writes concat ZZ.
// M_FUSE : 1x1 conv over 512ch + bias -> fp32 out.
// ---------------------------------------------------------------------------
template<int MODE>
__global__ __launch_bounds__(256)
void gemm_bt(const __bf16* __restrict__ A, long sAz,
             const __bf16* __restrict__ B, long sBz,
             int N, int K,
             __bf16* __restrict__ o0, __bf16* __restrict__ o1,
             __bf16* __restrict__ o2, __bf16* __restrict__ o3,
             long sOz,
             float* __restrict__ fout, long sFz,
             const float* __restrict__ bb0, const float* __restrict__ bb1,
             const float* __restrict__ bb2, const float* __restrict__ bb3,
             const float* __restrict__ resid, long sRz,
             __bf16* __restrict__ o4, __bf16* __restrict__ o5,
             const float* __restrict__ bb4, const float* __restrict__ bb5,
             const __bf16* __restrict__ A2)
{
  __shared__ __align__(16) __bf16 smem[8192];
  __bf16* As = smem;
  __bf16* Bs = smem + 4096;

  const int tid  = threadIdx.x;
  const int lane = tid & 63;
  const int w    = tid >> 6;
  const int wm   = (w >> 1) * 64;
  const int wn   = (w & 1) * 64;
  const int z    = blockIdx.z;
  const int by   = blockIdx.y;
  const int bn   = blockIdx.x * 128;

  int bmEff = by * 128;
  const __bf16* Ab;
  const __bf16* Bb;
  if constexpr (MODE == M_CONV) {
    bool isL = (by < 8);
    bmEff = (isL ? by : by - 8) * 128;
    Ab = isL ? A : A2;
    Bb = B + (long)((isL ? 0 : 2) + z) * sBz;
  } else {
    Ab = A + (long)z * sAz;
    Bb = B + (long)z * sBz;
  }

  f32x4 acc[4][4] = {};

  const int srow = lane >> 2;       // row within 16-row staging chunk
  const int skc  = (lane & 3) * 8;  // k-element offset within row

  for (int k0 = 0; k0 < K; k0 += 32) {
#pragma unroll
    for (int j = 0; j < 2; ++j) {
      int rbase = w * 32 + j * 16;
      stage16(Ab + (long)(bmEff + rbase + srow) * K + k0 + skc, As + rbase * 32);
    }
#pragma unroll
    for (int j = 0; j < 2; ++j) {
      int rbase = w * 32 + j * 16;
      stage16(Bb + (long)(bn + rbase + srow) * K + k0 + skc, Bs + rbase * 32);
    }
    __syncthreads();
    bf16x8 af[4], bfr[4];
#pragma unroll
    for (int t = 0; t < 4; ++t)
      af[t] = *(const bf16x8*)(As + (wm + t * 16 + (lane & 15)) * 32 + (lane >> 4) * 8);
#pragma unroll
    for (int t = 0; t < 4; ++t)
      bfr[t] = *(const bf16x8*)(Bs + (wn + t * 16 + (lane & 15)) * 32 + (lane >> 4) * 8);
#pragma unroll
    for (int mt = 0; mt < 4; ++mt)
#pragma unroll
      for (int nt = 0; nt < 4; ++nt)
        acc[mt][nt] = __builtin_amdgcn_mfma_f32_16x16x32_bf16(af[mt], bfr[nt], acc[mt][nt], 0, 0, 0);
    __syncthreads();
  }

#pragma unroll
  for (int mt = 0; mt < 4; ++mt) {
#pragma unroll
    for (int nt = 0; nt < 4; ++nt) {
#pragma unroll
      for (int r = 0; r < 4; ++r) {
        int m = bmEff + wm + mt * 16 + (lane >> 4) * 4 + r;
        int n = bn + wn + nt * 16 + (lane & 15);
        float v = acc[mt][nt][r];
        if constexpr (MODE == M_CONV) {
          int g = m >> 8, mm = m & 255;
          const float* bias; __bf16* op; bool vlay;
          if (by < 8) {
            bias = (g == 0) ? bb0 : (g == 1) ? bb1 : (g == 2) ? bb2 : bb3;
            op   = (g == 0) ? o0  : (g == 1) ? o1  : (g == 2) ? o2  : o3;
            vlay = (g == 2);
          } else {
            bias = g ? bb5 : bb4;
            op   = g ? o5  : o4;
            vlay = (g == 1);
          }
          float vv = v + bias[mm];
          if (vlay) op[(long)z * sOz + (long)mm * HWSZ + n] = (__bf16)vv;   // V: [c,p]
          else      op[(long)z * sOz + (long)n * CCH + mm] = (__bf16)vv;    // Q/K: [p,c]
        } else if constexpr (MODE == M_G1) {
          int bz = z & 1, brr = z >> 1;
          const float* rs = brr ? bb4 : resid;
          float vv = v + bb0[m] + rs[(long)bz * sRz + (long)m * HWSZ + n];
          o0[(long)bz * sOz + (long)n * 512 + m + brr * 256] = (__bf16)vv;  // ZZ: [p, 512]
        } else if constexpr (MODE == M_FUSE) {
          fout[(long)z * sFz + (long)m * HWSZ + n] = v + bb0[m];
        }
      }
    }
  }
}

// ---------------------------------------------------------------------------
// qk_stats: complete column-softmax stats in ONE kernel.
// Block = 64 q-columns (K-tile LDS-resident), one (z,br). Waves own disjoint
// i-rows; Q fragments load DIRECTLY from global to registers (no barriers in
// the loop). Running max/sumexp per q kept in registers over all 4096 i.
// grid (64, 2 z, 2 br), 256 threads.
// ---------------------------------------------------------------------------
__global__ __launch_bounds__(256)
void qk_stats(const __bf16* __restrict__ qs, const __bf16* __restrict__ qc,
              const __bf16* __restrict__ ks, const __bf16* __restrict__ kc,
              float* __restrict__ mst, float* __restrict__ lst)
{
  __shared__ __align__(16) __bf16 Kres[64 * 260];
  __shared__ float wm_[4][64], wl_[4][64];

  const int tid = threadIdx.x, lane = tid & 63, w = tid >> 6;
  const int quad = lane >> 4, l15 = lane & 15;
  const int qb = blockIdx.x * 64;
  const int z = blockIdx.y, br = blockIdx.z;
  const __bf16* Qt = (br ? qc : qs) + (long)z * 1048576;
  const __bf16* Kt = (br ? kc : ks) + (long)z * 1048576;

  for (int idx = tid; idx < 2048; idx += 256) {
    int r = idx >> 5, c8 = (idx & 31) * 8;
    *(bf16x8*)(Kres + r * 260 + c8) = *(const bf16x8*)(Kt + (long)(qb + r) * 256 + c8);
  }
  __syncthreads();

  float rm[4], rl[4];
#pragma unroll
  for (int nt = 0; nt < 4; ++nt) { rm[nt] = -3.0e38f; rl[nt] = 0.f; }

  for (int it = 0; it < 16; ++it) {
    const int i0 = it * 256 + w * 64;
    f32x4 accS[4][4] = {};
#pragma unroll
    for (int cs = 0; cs < 256; cs += 32) {
      bf16x8 a[4], b[4];
#pragma unroll
      for (int mt = 0; mt < 4; ++mt)
        a[mt] = *(const bf16x8*)(Qt + (long)(i0 + mt * 16 + l15) * 256 + cs + quad * 8);
#pragma unroll
      for (int nt = 0; nt < 4; ++nt)
        b[nt] = *(const bf16x8*)(Kres + (nt * 16 + l15) * 260 + cs + quad * 8);
#pragma unroll
      for (int mt = 0; mt < 4; ++mt)
#pragma unroll
        for (int nt = 0; nt < 4; ++nt)
          accS[mt][nt] = __builtin_amdgcn_mfma_f32_16x16x32_bf16(a[mt], b[nt], accS[mt][nt], 0, 0, 0);
    }
#pragma unroll
    for (int nt = 0; nt < 4; ++nt) {
      float mx = -3.0e38f;
#pragma unroll
      for (int mt = 0; mt < 4; ++mt)
#pragma unroll
        for (int r = 0; r < 4; ++r) mx = fmaxf(mx, accS[mt][nt][r]);
      float sl = 0.f;
#pragma unroll
      for (int mt = 0; mt < 4; ++mt)
#pragma unroll
        for (int r = 0; r < 4; ++r) sl += exp2_fast((accS[mt][nt][r] - mx) * LOG2E);
#pragma unroll
      for (int d = 16; d <= 32; d <<= 1) {
        float om = __shfl_xor(mx, d, 64);
        float ol = __shfl_xor(sl, d, 64);
        float nm = fmaxf(mx, om);
        sl = sl * exp2_fast((mx - nm) * LOG2E) + ol * exp2_fast((om - nm) * LOG2E);
        mx = nm;
      }
      float nm = fmaxf(rm[nt], mx);
      rl[nt] = rl[nt] * exp2_fast((rm[nt] - nm) * LOG2E) + sl * exp2_fast((mx - nm) * LOG2E);
      rm[nt] = nm;
    }
  }
  if (lane < 16) {
#pragma unroll
    for (int nt = 0; nt < 4; ++nt) { wm_[w][nt * 16 + lane] = rm[nt]; wl_[w][nt * 16 + lane] = rl[nt]; }
  }
  __syncthreads();
  if (tid < 64) {
    float m = -3.0e38f;
#pragma unroll
    for (int ww = 0; ww < 4; ++ww) m = fmaxf(m, wm_[ww][tid]);
    float l = 0.f;
#pragma unroll
    for (int ww = 0; ww < 4; ++ww)
      l += wl_[ww][tid] * exp2_fast((wm_[ww][tid] - m) * LOG2E);
    long o = ((long)(br * 2 + z)) * 4096 + qb + tid;
    mst[o] = m;
    lst[o] = 1.0f / l;
  }
}

// ---------------------------------------------------------------------------
// Fused recompute-S attention PV, barrier-light:
// G[i,j] = sum_q exp(S[i,q]-m_q)*linv_q * V[j,q].
// Block: i-tile 64 (Q LDS-resident), all j=256, one (z,br), one q-half.
// S-phase: K frags direct global->reg (waves own disjoint q) — NO barriers.
// V-phase: V frags direct global->reg (waves own disjoint j) — NO barriers.
// Only the P transpose (C-layout -> A-layout) round-trips LDS: 2 barriers
// per 128-q tile (was 26). fp32 partials, natural [i][j] layout.
// ---------------------------------------------------------------------------
__global__ __launch_bounds__(256)
void fused_pv(const __bf16* __restrict__ qs, const __bf16* __restrict__ qc,
              const __bf16* __restrict__ ks, const __bf16* __restrict__ kc,
              const __bf16* __restrict__ vs, const __bf16* __restrict__ vc,
              const float* __restrict__ mst, const float* __restrict__ lst,
              float* __restrict__ gacc)
{
  __shared__ __align__(16) __bf16 Qres[64 * 260];   // 33.3 KB
  __shared__ __align__(16) __bf16 Pl[64 * 132];     // 16.9 KB
  __shared__ float ms_[128], li_[128];

  const int tid = threadIdx.x, lane = tid & 63, w = tid >> 6;
  const int quad = lane >> 4, l15 = lane & 15;
  const int bi  = blockIdx.x * 64;
  const int zbr = blockIdx.y;           // br*2+z
  const int qh  = blockIdx.z;
  const int br = zbr >> 1, z = zbr & 1;
  const __bf16* Qt = (br ? qc : qs) + (long)z * 1048576;
  const __bf16* Kt = (br ? kc : ks) + (long)z * 1048576;
  const __bf16* Vv = (br ? vc : vs) + (long)z * 1048576;
  const float* msp = mst + (long)zbr * 4096;
  const float* lsp = lst + (long)zbr * 4096;
  float* go = gacc + ((long)qh * 4 + zbr) * 1048576;

  for (int idx = tid; idx < 2048; idx += 256) {
    int r = idx >> 5, c8 = (idx & 31) * 8;
    *(bf16x8*)(Qres + r * 260 + c8) = *(const bf16x8*)(Qt + (long)(bi + r) * 256 + c8);
  }

  f32x4 accO[4][4] = {};
  const int q0 = qh * 2048;

  for (int qc0 = q0; qc0 < q0 + 2048; qc0 += 128) {
    if (tid < 128) ms_[tid] = msp[qc0 + tid];
    else           li_[tid - 128] = lsp[qc0 + tid - 128];
    __syncthreads();   // ms_/li_ ready; prev V-phase Pl reads complete
    // --- S phase: no barriers, K frags direct to registers ---
    f32x4 accS[4][2] = {};
#pragma unroll
    for (int cs = 0; cs < 256; cs += 32) {
      bf16x8 aq[4], bk[2];
#pragma unroll
      for (int mt = 0; mt < 4; ++mt)
        aq[mt] = *(const bf16x8*)(Qres + (mt * 16 + l15) * 260 + cs + quad * 8);
#pragma unroll
      for (int nt = 0; nt < 2; ++nt)
        bk[nt] = *(const bf16x8*)(Kt + (long)(qc0 + w * 32 + nt * 16 + l15) * 256 + cs + quad * 8);
#pragma unroll
      for (int mt = 0; mt < 4; ++mt)
#pragma unroll
        for (int nt = 0; nt < 2; ++nt)
          accS[mt][nt] = __builtin_amdgcn_mfma_f32_16x16x32_bf16(aq[mt], bk[nt], accS[mt][nt], 0, 0, 0);
    }
    // P = exp(S - m_q)*linv_q -> LDS (transposed to [i][q])
#pragma unroll
    for (int mt = 0; mt < 4; ++mt)
#pragma unroll
      for (int nt = 0; nt < 2; ++nt) {
        int q = w * 32 + nt * 16 + l15;
        float mq = ms_[q], lq = li_[q];
#pragma unroll
        for (int r = 0; r < 4; ++r) {
          int i = mt * 16 + quad * 4 + r;
          Pl[i * 132 + q] = (__bf16)(exp2_fast((accS[mt][nt][r] - mq) * LOG2E) * lq);
        }
      }
    __syncthreads();
    // --- V phase: no barriers, V frags direct to registers ---
#pragma unroll
    for (int qs0 = 0; qs0 < 128; qs0 += 32) {
      bf16x8 ap[4], bv[4];
#pragma unroll
      for (int mt = 0; mt < 4; ++mt)
        ap[mt] = *(const bf16x8*)(Pl + (mt * 16 + l15) * 132 + qs0 + quad * 8);
#pragma unroll
      for (int nt = 0; nt < 4; ++nt)
        bv[nt] = *(const bf16x8*)(Vv + (long)(w * 64 + nt * 16 + l15) * 4096 + qc0 + qs0 + quad * 8);
#pragma unroll
      for (int mt = 0; mt < 4; ++mt)
#pragma unroll
        for (int nt = 0; nt < 4; ++nt)
          accO[mt][nt] = __builtin_amdgcn_mfma_f32_16x16x32_bf16(ap[mt], bv[nt], accO[mt][nt], 0, 0, 0);
    }
  }
  // natural-layout fp32 partial store (coalesced 64B segments)
#pragma unroll
  for (int mt = 0; mt < 4; ++mt)
#pragma unroll
    for (int nt = 0; nt < 4; ++nt)
#pragma unroll
      for (int r = 0; r < 4; ++r) {
        int i = mt * 16 + quad * 4 + r;
        int j = w * 64 + nt * 16 + l15;
        go[(long)(bi + i) * 256 + j] = accO[mt][nt][r];
      }
}

// ---------------------------------------------------------------------------
// Sum the two q-half partials (natural [i][j] fp32) and write GTS in the
// raw-reshape layout gt[p*256+ci], p=(i&15)*256+j, ci=i>>4 — via LDS
// transpose. grid (jg 4, v 16, zbr 4), 256 threads.
__global__ __launch_bounds__(256)
void gsum_reshape(const float* __restrict__ ga, __bf16* __restrict__ gt) {
  __shared__ __bf16 lds[64 * 260];
  const int t = threadIdx.x, lane = t & 63, w = t >> 6;
  const int zbr = blockIdx.z;
  const int v   = blockIdx.y;
  const int jg  = blockIdx.x;
  const float* g0 = ga + (long)zbr * 1048576;
  const float* g1 = g0 + 4194304;
  for (int ci0 = 0; ci0 < 256; ci0 += 4) {
    int ci = ci0 + w;
    long src = (long)(ci * 16 + v) * 256 + jg * 64 + lane;
    lds[lane * 260 + ci] = (__bf16)(g0[src] + g1[src]);
  }
  __syncthreads();
  __bf16* out = gt + (long)zbr * 1048576 + ((long)v * 256 + jg * 64) * 256;
#pragma unroll
  for (int pp = 0; pp < 8; ++pp) {
    int idx = pp * 256 + t;
    int row = idx >> 5, c8 = (idx & 31) * 8;
    *(bf16x8*)(out + (long)row * 256 + c8) = *(const bf16x8*)(lds + row * 260 + c8);
  }
}

// ---------------------------------------------------------------------------
// Fl/Fv [b][256][4096] fp32  ->  Xt [img][4096][256] bf16 (img: Fl b0, Fl b1, Fv b0, Fv b1)
__global__ void transpose_cvt(const float* __restrict__ F0, const float* __restrict__ F1,
                              __bf16* __restrict__ Xt) {
  __shared__ float tile[32][33];
  int img = blockIdx.z;
  const float* src = (img < 2 ? F0 : F1) + (long)(img & 1) * (CCH * HWSZ);
  __bf16* dst = Xt + (long)img * (HWSZ * CCH);
  int p0 = blockIdx.x * 32, c0 = blockIdx.y * 32;
  int tx = threadIdx.x, ty = threadIdx.y;
#pragma unroll
  for (int j = 0; j < 32; j += 8)
    tile[ty + j][tx] = src[(long)(c0 + ty + j) * HWSZ + p0 + tx];
  __syncthreads();
#pragma unroll
  for (int j = 0; j < 32; j += 8)
    dst[(long)(p0 + ty + j) * CCH + c0 + tx] = (__bf16)tile[tx][ty + j];
}

// Xt [img][4096][256] -> im2col Cc [img][4096][2304], k = t*256+ci, zero-padded borders
__global__ void im2col_k(const __bf16* __restrict__ Xt, __bf16* __restrict__ Cc) {
  int img = blockIdx.y;
  int e = blockIdx.x * 256 + threadIdx.x;          // < 4096*288
  int p = e / 288;
  int c8 = e - p * 288;
  int t = c8 >> 5;                                 // 0..8
  int ci0 = (c8 & 31) * 8;
  int dy = t / 3 - 1, dx = t - (t / 3) * 3 - 1;
  int y = p >> 6, x = p & 63;
  int yy = y + dy, xx = x + dx;
  const __bf16* src = Xt + (long)img * (HWSZ * CCH);
  __bf16* dst = Cc + (long)img * 9437184 + (long)p * 2304 + t * 256 + ci0;
  uint4 v = make_uint4(0u, 0u, 0u, 0u);
  if ((unsigned)yy < 64u && (unsigned)xx < 64u)
    v = *(const uint4*)(src + (long)(yy * 64 + xx) * CCH + ci0);
  *(uint4*)dst = v;
}

// W[co][ci][3][3] fp32 -> A[co][t*256+ci] bf16, stacked: AL (Wqs,Wks,Wvs,Wqc), AV (Wkc,Wvc)
struct W6 { const float* w[6]; };
__global__ void repack_w3(W6 wp, __bf16* __restrict__ AL, __bf16* __restrict__ AV) {
  int zi = blockIdx.y;
  int e = blockIdx.x * 256 + threadIdx.x;          // < 256*2304
  int co = e / 2304;
  int rem = e - co * 2304;
  int t = rem >> 8, ci = rem & 255;
  float v = wp.w[zi][(long)co * 2304 + ci * 9 + t];
  __bf16* dst = (zi < 4) ? (AL + (long)zi * 256 * 2304) : (AV + (long)(zi - 4) * 256 * 2304);
  dst[(long)co * 2304 + rem] = (__bf16)v;
}

__global__ void cvt_bf(const float* __restrict__ s, __bf16* __restrict__ d, int n) {
  int i = blockIdx.x * 256 + threadIdx.x;
  if (i < n) d[i] = (__bf16)s[i];
}

// ---------------------------------------------------------------------------
extern "C" void kernel_launch(void* const* d_in, const int* in_sizes, int n_in,
                              void* d_out, int out_size, void* d_ws, size_t ws_size,
                              hipStream_t stream) {
  const float* Fl  = (const float*)d_in[0];
  const float* Fv  = (const float*)d_in[1];
  const float* Wqs = (const float*)d_in[2];  const float* bqs = (const float*)d_in[3];
  const float* Wks = (const float*)d_in[4];  const float* bks = (const float*)d_in[5];
  const float* Wvs = (const float*)d_in[6];  const float* bvs = (const float*)d_in[7];
  const float* Wqc = (const float*)d_in[8];  const float* bqc = (const float*)d_in[9];
  const float* Wkc = (const float*)d_in[10]; const float* bkc = (const float*)d_in[11];
  const float* Wvc = (const float*)d_in[12]; const float* bvc = (const float*)d_in[13];
  const float* Wgs = (const float*)d_in[14]; const float* bgs = (const float*)d_in[15];
  const float* Wfu = (const float*)d_in[16]; const float* bfu = (const float*)d_in[17];

  char* ws = (char*)d_ws;
  size_t off = 0;
  auto take = [&](size_t bytes) -> void* {
    void* p = ws + off; off = (off + bytes + 255) & ~(size_t)255; return p;
  };
  __bf16* QST  = (__bf16*)take(4194304);   // Qs^T  [b][4096][256]
  __bf16* KST  = (__bf16*)take(4194304);
  __bf16* QCT  = (__bf16*)take(4194304);
  __bf16* KCT  = (__bf16*)take(4194304);
  __bf16* VS   = (__bf16*)take(4194304);   // Vs    [b][256][4096]
  __bf16* VC   = (__bf16*)take(4194304);
  __bf16* GTS  = (__bf16*)take(8388608);   // G (reshape layout) [br*2+z][4096][256]
  __bf16* ZZ   = (__bf16*)take(8388608);   // concat [b][4096][512]
  __bf16* AL   = (__bf16*)take(4718592);   // stacked conv weights [1024][2304]
  __bf16* AV   = (__bf16*)take(2359296);   // [512][2304]
  __bf16* WGSb = (__bf16*)take(131072);
  __bf16* WFSb = (__bf16*)take(262144);
  float*  MST  = (float*)take(65536);      // [br*2+z][4096]
  float*  LST  = (float*)take(65536);
  size_t ovl = off;                         // overlay region
  __bf16* Xt = (__bf16*)take(8388608);      // conv phase only
  __bf16* Cc = (__bf16*)take(75497472);     // conv phase only
  size_t needConv = off;
  float* GACC = (float*)(ws + ovl);         // attn phase: [2 qh][4 zbr][4096*256] fp32 = 32 MB
  size_t needAttn = ovl + 33554432;
  size_t need = needConv > needAttn ? needConv : needAttn;
  if (ws_size < need) return;               // fail cleanly instead of faulting

  const long Z1 = 1048576;                  // per-batch stride (elements)

  transpose_cvt<<<dim3(128, 8, 4), dim3(32, 8), 0, stream>>>(Fl, Fv, Xt);
  im2col_k<<<dim3(4608, 4), 256, 0, stream>>>(Xt, Cc);
  W6 wp; wp.w[0]=Wqs; wp.w[1]=Wks; wp.w[2]=Wvs; wp.w[3]=Wqc; wp.w[4]=Wkc; wp.w[5]=Wvc;
  repack_w3<<<dim3(2304, 6), 256, 0, stream>>>(wp, AL, AV);
  cvt_bf<<<256, 256, 0, stream>>>(Wgs, WGSb, 65536);
  cvt_bf<<<512, 256, 0, stream>>>(Wfu, WFSb, 131072);

  // merged conv3x3 GEMM: y<8 -> AL x Cc(Fl imgs), y>=8 -> AV x Cc(Fv imgs)
  gemm_bt<M_CONV><<<dim3(32, 12, 2), 256, 0, stream>>>(
      AL, 0, Cc, 9437184, 4096, 2304,
      QST, KST, VS, QCT, Z1,
      nullptr, 0,
      bqs, bks, bvs, bqc,
      nullptr, 0,
      KCT, VC, bkc, bvc, AV);

  // complete column-softmax stats, one kernel, all (br,z)
  qk_stats<<<dim3(64, 2, 2), 256, 0, stream>>>(QST, QCT, KST, KCT, MST, LST);

  // fused recompute-S PV for all (br, z, q-half) -> natural-layout fp32 partials
  fused_pv<<<dim3(64, 4, 2), 256, 0, stream>>>(
      QST, QCT, KST, KCT, VS, VC, MST, LST, GACC);
  // sum partials + raw-reshape -> GTS (coalesced both sides)
  gsum_reshape<<<dim3(4, 16, 4), 256, 0, stream>>>(GACC, GTS);

  // 1x1 conv + bias + residual -> ZZ (both branches in one dispatch)
  gemm_bt<M_G1><<<dim3(32, 2, 4), 256, 0, stream>>>(
      WGSb, 0, GTS, Z1, 4096, 256,
      ZZ, nullptr, nullptr, nullptr, (long)2097152,
      nullptr, 0,
      bgs, nullptr, nullptr, nullptr,
      Fl, Z1,
      nullptr, nullptr, Fv, nullptr, nullptr);
  // fuse conv 1x1 over 512 channels -> fp32 out
  gemm_bt<M_FUSE><<<dim3(32, 2, 2), 256, 0, stream>>>(
      WFSb, 0, ZZ, (long)2097152, 4096, 512,
      nullptr, nullptr, nullptr, nullptr, 0,
      (float*)d_out, Z1,
      bfu, nullptr, nullptr, nullptr,
      nullptr, 0,
      nullptr, nullptr, nullptr, nullptr, nullptr);
}

// Round 7
// 467.364 us; speedup vs baseline: 1.1272x; 1.1272x over previous
//
#include <hip/hip_runtime.h>

typedef __bf16 bf16x4 __attribute__((ext_vector_type(4)));
typedef __bf16 bf16x8 __attribute__((ext_vector_type(8)));
typedef float  f32x4  __attribute__((ext_vector_type(4)));

#define HWSZ 4096
#define CCH  256
#define LOG2E 1.44269504088896340736f

__device__ __forceinline__ float exp2_fast(float x) {
#if __has_builtin(__builtin_amdgcn_exp2f)
  return __builtin_amdgcn_exp2f(x);
#else
  return exp2f(x);
#endif
}

// stage 16B per lane into LDS; lane's data lands at lds_base + lane*16B
__device__ __forceinline__ void stage16(const __bf16* g, __bf16* ldsBase) {
#if __has_builtin(__builtin_amdgcn_global_load_lds)
  __builtin_amdgcn_global_load_lds(
      (const __attribute__((address_space(1))) void*)g,
      (__attribute__((address_space(3))) void*)ldsBase, 16, 0, 0);
#else
  int lane = threadIdx.x & 63;
  *(bf16x8*)(ldsBase + lane * 8) = *(const bf16x8*)g;
#endif
}

// ---------------------------------------------------------------------------
// Merged conv3x3 GEMM (128x128x32 MFMA): by<8 -> A=AL (Qs,Ks,Vs,Qc from Fl),
// else A=AV (Kc,Vc from Fv). B = im2col Cc [img][4096][2304].
// ---------------------------------------------------------------------------
__global__ __launch_bounds__(256)
void gemm_conv(const __bf16* __restrict__ AL, const __bf16* __restrict__ AV,
               const __bf16* __restrict__ Cc,
               __bf16* __restrict__ qst, __bf16* __restrict__ kst,
               __bf16* __restrict__ vs,  __bf16* __restrict__ qct,
               __bf16* __restrict__ kct, __bf16* __restrict__ vc,
               const float* __restrict__ bqs, const float* __restrict__ bks,
               const float* __restrict__ bvs, const float* __restrict__ bqc,
               const float* __restrict__ bkc, const float* __restrict__ bvc)
{
  __shared__ __align__(16) __bf16 smem[8192];
  __bf16* As = smem;
  __bf16* Bs = smem + 4096;

  const int tid  = threadIdx.x;
  const int lane = tid & 63;
  const int w    = tid >> 6;
  const int wm   = (w >> 1) * 64;
  const int wn   = (w & 1) * 64;
  const int z    = blockIdx.z;
  const int by   = blockIdx.y;
  const int bn   = blockIdx.x * 128;
  const int K    = 2304;

  const bool isL = (by < 8);
  const int bm = (isL ? by : by - 8) * 128;
  const __bf16* Ab = isL ? AL : AV;
  const __bf16* Bb = Cc + (long)((isL ? 0 : 2) + z) * 9437184;

  f32x4 acc[4][4] = {};
  const int srow = lane >> 2;
  const int skc  = (lane & 3) * 8;

  for (int k0 = 0; k0 < K; k0 += 32) {
#pragma unroll
    for (int j = 0; j < 2; ++j) {
      int rbase = w * 32 + j * 16;
      stage16(Ab + (long)(bm + rbase + srow) * K + k0 + skc, As + rbase * 32);
    }
#pragma unroll
    for (int j = 0; j < 2; ++j) {
      int rbase = w * 32 + j * 16;
      stage16(Bb + (long)(bn + rbase + srow) * K + k0 + skc, Bs + rbase * 32);
    }
    __syncthreads();
    bf16x8 af[4], bfr[4];
#pragma unroll
    for (int t = 0; t < 4; ++t)
      af[t] = *(const bf16x8*)(As + (wm + t * 16 + (lane & 15)) * 32 + (lane >> 4) * 8);
#pragma unroll
    for (int t = 0; t < 4; ++t)
      bfr[t] = *(const bf16x8*)(Bs + (wn + t * 16 + (lane & 15)) * 32 + (lane >> 4) * 8);
#pragma unroll
    for (int mt = 0; mt < 4; ++mt)
#pragma unroll
      for (int nt = 0; nt < 4; ++nt)
        acc[mt][nt] = __builtin_amdgcn_mfma_f32_16x16x32_bf16(af[mt], bfr[nt], acc[mt][nt], 0, 0, 0);
    __syncthreads();
  }

#pragma unroll
  for (int mt = 0; mt < 4; ++mt) {
#pragma unroll
    for (int nt = 0; nt < 4; ++nt) {
#pragma unroll
      for (int r = 0; r < 4; ++r) {
        int m = bm + wm + mt * 16 + (lane >> 4) * 4 + r;
        int n = bn + wn + nt * 16 + (lane & 15);
        int g = m >> 8, mm = m & 255;
        const float* bias; __bf16* op; bool vlay;
        if (isL) {
          bias = (g == 0) ? bqs : (g == 1) ? bks : (g == 2) ? bvs : bqc;
          op   = (g == 0) ? qst : (g == 1) ? kst : (g == 2) ? vs  : qct;
          vlay = (g == 2);
        } else {
          bias = g ? bvc : bkc;
          op   = g ? vc  : kct;
          vlay = (g == 1);
        }
        float vv = acc[mt][nt][r] + bias[mm];
        if (vlay) op[(long)z * 1048576 + (long)mm * HWSZ + n] = (__bf16)vv;   // V: [c,p]
        else      op[(long)z * 1048576 + (long)n * CCH + mm] = (__bf16)vv;    // Q/K: [p,c]
      }
    }
  }
}

// ---------------------------------------------------------------------------
// qk_stats: full column-softmax stats (max/sumexp over i, per q).
// 1-D grid 256 blocks, XCD-swizzled: group g = lid&3 -> (z, br); qb = lid>>2.
// K-tile LDS-resident; Q fragments direct global->reg; running stats in regs.
// ---------------------------------------------------------------------------
__global__ __launch_bounds__(256)
void qk_stats(const __bf16* __restrict__ qs, const __bf16* __restrict__ qc,
              const __bf16* __restrict__ ks, const __bf16* __restrict__ kc,
              float* __restrict__ mst, float* __restrict__ lst)
{
  __shared__ __align__(16) __bf16 Kres[64 * 260];
  __shared__ float wm_[4][64], wl_[4][64];

  const int tid = threadIdx.x, lane = tid & 63, w = tid >> 6;
  const int quad = lane >> 4, l15 = lane & 15;
  const int lid = blockIdx.x;
  const int g = lid & 3;
  const int z = g & 1, br = g >> 1;
  const int qb = (lid >> 2) * 64;
  const __bf16* Qt = (br ? qc : qs) + (long)z * 1048576;
  const __bf16* Kt = (br ? kc : ks) + (long)z * 1048576;

  for (int idx = tid; idx < 2048; idx += 256) {
    int r = idx >> 5, c8 = (idx & 31) * 8;
    *(bf16x8*)(Kres + r * 260 + c8) = *(const bf16x8*)(Kt + (long)(qb + r) * 256 + c8);
  }
  __syncthreads();

  float rm[4], rl[4];
#pragma unroll
  for (int nt = 0; nt < 4; ++nt) { rm[nt] = -3.0e38f; rl[nt] = 0.f; }

  for (int it = 0; it < 16; ++it) {
    const int i0 = it * 256 + w * 64;
    f32x4 accS[4][4] = {};
#pragma unroll
    for (int cs = 0; cs < 256; cs += 32) {
      bf16x8 a[4], b[4];
#pragma unroll
      for (int mt = 0; mt < 4; ++mt)
        a[mt] = *(const bf16x8*)(Qt + (long)(i0 + mt * 16 + l15) * 256 + cs + quad * 8);
#pragma unroll
      for (int nt = 0; nt < 4; ++nt)
        b[nt] = *(const bf16x8*)(Kres + (nt * 16 + l15) * 260 + cs + quad * 8);
#pragma unroll
      for (int mt = 0; mt < 4; ++mt)
#pragma unroll
        for (int nt = 0; nt < 4; ++nt)
          accS[mt][nt] = __builtin_amdgcn_mfma_f32_16x16x32_bf16(a[mt], b[nt], accS[mt][nt], 0, 0, 0);
    }
#pragma unroll
    for (int nt = 0; nt < 4; ++nt) {
      float mx = -3.0e38f;
#pragma unroll
      for (int mt = 0; mt < 4; ++mt)
#pragma unroll
        for (int r = 0; r < 4; ++r) mx = fmaxf(mx, accS[mt][nt][r]);
      float sl = 0.f;
#pragma unroll
      for (int mt = 0; mt < 4; ++mt)
#pragma unroll
        for (int r = 0; r < 4; ++r) sl += exp2_fast((accS[mt][nt][r] - mx) * LOG2E);
#pragma unroll
      for (int d = 16; d <= 32; d <<= 1) {
        float om = __shfl_xor(mx, d, 64);
        float ol = __shfl_xor(sl, d, 64);
        float nm = fmaxf(mx, om);
        sl = sl * exp2_fast((mx - nm) * LOG2E) + ol * exp2_fast((om - nm) * LOG2E);
        mx = nm;
      }
      float nm = fmaxf(rm[nt], mx);
      rl[nt] = rl[nt] * exp2_fast((rm[nt] - nm) * LOG2E) + sl * exp2_fast((mx - nm) * LOG2E);
      rm[nt] = nm;
    }
  }
  if (lane < 16) {
#pragma unroll
    for (int nt = 0; nt < 4; ++nt) { wm_[w][nt * 16 + lane] = rm[nt]; wl_[w][nt * 16 + lane] = rl[nt]; }
  }
  __syncthreads();
  if (tid < 64) {
    float m = -3.0e38f;
#pragma unroll
    for (int ww = 0; ww < 4; ++ww) m = fmaxf(m, wm_[ww][tid]);
    float l = 0.f;
#pragma unroll
    for (int ww = 0; ww < 4; ++ww)
      l += wl_[ww][tid] * exp2_fast((wm_[ww][tid] - m) * LOG2E);
    long o = ((long)(br * 2 + z)) * 4096 + qb + tid;
    mst[o] = m;
    lst[o] = 1.0f / l;
  }
}

// ---------------------------------------------------------------------------
// Fused recompute-S PV, hybrid: staged K (global_load_lds queue), direct-reg V,
// per-thread register stats. 1-D grid 512, XCD-swizzled: g = lid&7 ->
// (zbr = g>>1, qh = g&1); i-block = lid>>3. 17 barriers per 128-q tile.
// ---------------------------------------------------------------------------
__global__ __launch_bounds__(256)
void fused_pv(const __bf16* __restrict__ qs, const __bf16* __restrict__ qc,
              const __bf16* __restrict__ ks, const __bf16* __restrict__ kc,
              const __bf16* __restrict__ vs, const __bf16* __restrict__ vc,
              const float* __restrict__ mst, const float* __restrict__ lst,
              float* __restrict__ gacc)
{
  __shared__ __align__(16) __bf16 Qres[64 * 260];   // 33.3 KB
  __shared__ __align__(16) __bf16 Pl[64 * 132];     // 16.9 KB
  __shared__ __align__(16) __bf16 Kst[128 * 32];    //  8.0 KB

  const int tid = threadIdx.x, lane = tid & 63, w = tid >> 6;
  const int quad = lane >> 4, l15 = lane & 15;
  const int lid = blockIdx.x;
  const int g   = lid & 7;
  const int zbr = g >> 1;
  const int qh  = g & 1;
  const int bi  = (lid >> 3) * 64;
  const int br = zbr >> 1, z = zbr & 1;
  const __bf16* Qt = (br ? qc : qs) + (long)z * 1048576;
  const __bf16* Kt = (br ? kc : ks) + (long)z * 1048576;
  const __bf16* Vv = (br ? vc : vs) + (long)z * 1048576;
  const float* msp = mst + (long)zbr * 4096;
  const float* lsp = lst + (long)zbr * 4096;
  float* go = gacc + ((long)qh * 4 + zbr) * 1048576;

  for (int idx = tid; idx < 2048; idx += 256) {
    int r = idx >> 5, c8 = (idx & 31) * 8;
    *(bf16x8*)(Qres + r * 260 + c8) = *(const bf16x8*)(Qt + (long)(bi + r) * 256 + c8);
  }

  f32x4 accO[4][4] = {};
  const int srow = lane >> 2, skc = (lane & 3) * 8;
  const int q0 = qh * 2048;

  for (int qc0 = q0; qc0 < q0 + 2048; qc0 += 128) {
    // --- S phase: staged K, 2 barriers/cs ---
    f32x4 accS[4][2] = {};
#pragma unroll
    for (int cs = 0; cs < 256; cs += 32) {
#pragma unroll
      for (int jj = 0; jj < 2; ++jj) {
        int rbase = w * 32 + jj * 16;
        stage16(Kt + (long)(qc0 + rbase + srow) * 256 + cs + skc, Kst + rbase * 32);
      }
      __syncthreads();
      bf16x8 aq[4], bk[2];
#pragma unroll
      for (int mt = 0; mt < 4; ++mt)
        aq[mt] = *(const bf16x8*)(Qres + (mt * 16 + l15) * 260 + cs + quad * 8);
#pragma unroll
      for (int nt = 0; nt < 2; ++nt)
        bk[nt] = *(const bf16x8*)(Kst + (w * 32 + nt * 16 + l15) * 32 + quad * 8);
#pragma unroll
      for (int mt = 0; mt < 4; ++mt)
#pragma unroll
        for (int nt = 0; nt < 2; ++nt)
          accS[mt][nt] = __builtin_amdgcn_mfma_f32_16x16x32_bf16(aq[mt], bk[nt], accS[mt][nt], 0, 0, 0);
      __syncthreads();
    }
    // P = exp(S - m_q)*linv_q -> LDS (stats from global, per-thread regs)
#pragma unroll
    for (int nt = 0; nt < 2; ++nt) {
      int q = w * 32 + nt * 16 + l15;
      float mq = msp[qc0 + q], lq = lsp[qc0 + q];
#pragma unroll
      for (int mt = 0; mt < 4; ++mt)
#pragma unroll
        for (int r = 0; r < 4; ++r) {
          int i = mt * 16 + quad * 4 + r;
          Pl[i * 132 + q] = (__bf16)(exp2_fast((accS[mt][nt][r] - mq) * LOG2E) * lq);
        }
    }
    __syncthreads();
    // --- V phase: direct-reg V (independent, hoistable), no barriers ---
#pragma unroll
    for (int qs0 = 0; qs0 < 128; qs0 += 32) {
      bf16x8 ap[4], bv[4];
#pragma unroll
      for (int mt = 0; mt < 4; ++mt)
        ap[mt] = *(const bf16x8*)(Pl + (mt * 16 + l15) * 132 + qs0 + quad * 8);
#pragma unroll
      for (int nt = 0; nt < 4; ++nt)
        bv[nt] = *(const bf16x8*)(Vv + (long)(w * 64 + nt * 16 + l15) * 4096 + qc0 + qs0 + quad * 8);
#pragma unroll
      for (int mt = 0; mt < 4; ++mt)
#pragma unroll
        for (int nt = 0; nt < 4; ++nt)
          accO[mt][nt] = __builtin_amdgcn_mfma_f32_16x16x32_bf16(ap[mt], bv[nt], accO[mt][nt], 0, 0, 0);
    }
  }
  // natural-layout fp32 partial store (coalesced 64B segments)
#pragma unroll
  for (int mt = 0; mt < 4; ++mt)
#pragma unroll
    for (int nt = 0; nt < 4; ++nt)
#pragma unroll
      for (int r = 0; r < 4; ++r) {
        int i = mt * 16 + quad * 4 + r;
        int j = w * 64 + nt * 16 + l15;
        go[(long)(bi + i) * 256 + j] = accO[mt][nt][r];
      }
}

// ---------------------------------------------------------------------------
// Sum the two q-half partials and write GTS in raw-reshape layout via LDS
// transpose. grid (jg 4, v 16, zbr 4), 256 threads.
__global__ __launch_bounds__(256)
void gsum_reshape(const float* __restrict__ ga, __bf16* __restrict__ gt) {
  __shared__ __bf16 lds[64 * 260];
  const int t = threadIdx.x, lane = t & 63, w = t >> 6;
  const int zbr = blockIdx.z;
  const int v   = blockIdx.y;
  const int jg  = blockIdx.x;
  const float* g0 = ga + (long)zbr * 1048576;
  const float* g1 = g0 + 4194304;
  for (int ci0 = 0; ci0 < 256; ci0 += 4) {
    int ci = ci0 + w;
    long src = (long)(ci * 16 + v) * 256 + jg * 64 + lane;
    lds[lane * 260 + ci] = (__bf16)(g0[src] + g1[src]);
  }
  __syncthreads();
  __bf16* out = gt + (long)zbr * 1048576 + ((long)v * 256 + jg * 64) * 256;
#pragma unroll
  for (int pp = 0; pp < 8; ++pp) {
    int idx = pp * 256 + t;
    int row = idx >> 5, c8 = (idx & 31) * 8;
    *(bf16x8*)(out + (long)row * 256 + c8) = *(const bf16x8*)(lds + row * 260 + c8);
  }
}

// ---------------------------------------------------------------------------
// Weight fold: WT = [Wfu_l*Wgs | Wfu_v*Wgs | Wfu_l | Wfu_v] (bf16 [256][1024]),
// biasT[co] = bfu[co] + sum_c (Wfu[co][c]+Wfu[co][c+256]) * bgs[c].
// grid 256 blocks (co), 256 threads (k').
__global__ __launch_bounds__(256)
void wcomb(const float* __restrict__ Wgs, const float* __restrict__ bgs,
           const float* __restrict__ Wfu, const float* __restrict__ bfu,
           __bf16* __restrict__ WT, float* __restrict__ biasT)
{
  const int co = blockIdx.x, t = threadIdx.x;
  const float* wrow = Wfu + (long)co * 512;
  float accs = 0.f, accc = 0.f;
  for (int c = 0; c < 256; ++c) {
    float gv = Wgs[(long)c * 256 + t];
    accs = fmaf(wrow[c], gv, accs);
    accc = fmaf(wrow[c + 256], gv, accc);
  }
  __bf16* o = WT + (long)co * 1024;
  o[t]       = (__bf16)accs;
  o[256 + t] = (__bf16)accc;
  o[512 + t] = (__bf16)wrow[t];
  o[768 + t] = (__bf16)wrow[256 + t];
  __shared__ float red[256];
  red[t] = (wrow[t] + wrow[t + 256]) * bgs[t];
  __syncthreads();
  for (int s = 128; s > 0; s >>= 1) {
    if (t < s) red[t] += red[t + s];
    __syncthreads();
  }
  if (t == 0) biasT[co] = bfu[co] + red[0];
}

// ---------------------------------------------------------------------------
// Tail GEMM: out[z][co][p] = sum_k WT[co][k] * Bcat[z][p][k] + biasT[co],
// Bcat k-groups: 0 GTS_s, 1 GTS_c, 2 Xt(Fl), 3 Xt(Fv). grid (32, 2, 2).
__global__ __launch_bounds__(256)
void tail_gemm(const __bf16* __restrict__ WT, const __bf16* __restrict__ GTS,
               const __bf16* __restrict__ Xt, const float* __restrict__ biasT,
               float* __restrict__ out)
{
  __shared__ __align__(16) __bf16 smem[8192];
  __bf16* As = smem;
  __bf16* Bs = smem + 4096;

  const int tid  = threadIdx.x;
  const int lane = tid & 63;
  const int w    = tid >> 6;
  const int wm   = (w >> 1) * 64;
  const int wn   = (w & 1) * 64;
  const int z    = blockIdx.z;
  const int bm   = blockIdx.y * 128;
  const int bn   = blockIdx.x * 128;

  const __bf16* Bsel[4] = {
    GTS + (long)z * 1048576, GTS + (long)(2 + z) * 1048576,
    Xt  + (long)z * 1048576, Xt  + (long)(2 + z) * 1048576
  };

  f32x4 acc[4][4] = {};
  const int srow = lane >> 2;
  const int skc  = (lane & 3) * 8;

  for (int k0 = 0; k0 < 1024; k0 += 32) {
    const __bf16* Bb = Bsel[k0 >> 8];
    const int kk = k0 & 255;
#pragma unroll
    for (int j = 0; j < 2; ++j) {
      int rbase = w * 32 + j * 16;
      stage16(WT + (long)(bm + rbase + srow) * 1024 + k0 + skc, As + rbase * 32);
    }
#pragma unroll
    for (int j = 0; j < 2; ++j) {
      int rbase = w * 32 + j * 16;
      stage16(Bb + (long)(bn + rbase + srow) * 256 + kk + skc, Bs + rbase * 32);
    }
    __syncthreads();
    bf16x8 af[4], bfr[4];
#pragma unroll
    for (int t = 0; t < 4; ++t)
      af[t] = *(const bf16x8*)(As + (wm + t * 16 + (lane & 15)) * 32 + (lane >> 4) * 8);
#pragma unroll
    for (int t = 0; t < 4; ++t)
      bfr[t] = *(const bf16x8*)(Bs + (wn + t * 16 + (lane & 15)) * 32 + (lane >> 4) * 8);
#pragma unroll
    for (int mt = 0; mt < 4; ++mt)
#pragma unroll
      for (int nt = 0; nt < 4; ++nt)
        acc[mt][nt] = __builtin_amdgcn_mfma_f32_16x16x32_bf16(af[mt], bfr[nt], acc[mt][nt], 0, 0, 0);
    __syncthreads();
  }

#pragma unroll
  for (int mt = 0; mt < 4; ++mt)
#pragma unroll
    for (int nt = 0; nt < 4; ++nt)
#pragma unroll
      for (int r = 0; r < 4; ++r) {
        int m = bm + wm + mt * 16 + (lane >> 4) * 4 + r;
        int n = bn + wn + nt * 16 + (lane & 15);
        out[((long)z * 256 + m) * HWSZ + n] = acc[mt][nt][r] + biasT[m];
      }
}

// ---------------------------------------------------------------------------
// Fl/Fv [b][256][4096] fp32 -> Xt [img][4096][256] bf16 (Fl b0, Fl b1, Fv b0, Fv b1)
__global__ void transpose_cvt(const float* __restrict__ F0, const float* __restrict__ F1,
                              __bf16* __restrict__ Xt) {
  __shared__ float tile[32][33];
  int img = blockIdx.z;
  const float* src = (img < 2 ? F0 : F1) + (long)(img & 1) * (CCH * HWSZ);
  __bf16* dst = Xt + (long)img * (HWSZ * CCH);
  int p0 = blockIdx.x * 32, c0 = blockIdx.y * 32;
  int tx = threadIdx.x, ty = threadIdx.y;
#pragma unroll
  for (int j = 0; j < 32; j += 8)
    tile[ty + j][tx] = src[(long)(c0 + ty + j) * HWSZ + p0 + tx];
  __syncthreads();
#pragma unroll
  for (int j = 0; j < 32; j += 8)
    dst[(long)(p0 + ty + j) * CCH + c0 + tx] = (__bf16)tile[tx][ty + j];
}

// Xt -> im2col Cc [img][4096][2304], k = t*256+ci, zero-padded borders
__global__ void im2col_k(const __bf16* __restrict__ Xt, __bf16* __restrict__ Cc) {
  int img = blockIdx.y;
  int e = blockIdx.x * 256 + threadIdx.x;
  int p = e / 288;
  int c8 = e - p * 288;
  int t = c8 >> 5;
  int ci0 = (c8 & 31) * 8;
  int dy = t / 3 - 1, dx = t - (t / 3) * 3 - 1;
  int y = p >> 6, x = p & 63;
  int yy = y + dy, xx = x + dx;
  const __bf16* src = Xt + (long)img * (HWSZ * CCH);
  __bf16* dst = Cc + (long)img * 9437184 + (long)p * 2304 + t * 256 + ci0;
  uint4 v = make_uint4(0u, 0u, 0u, 0u);
  if ((unsigned)yy < 64u && (unsigned)xx < 64u)
    v = *(const uint4*)(src + (long)(yy * 64 + xx) * CCH + ci0);
  *(uint4*)dst = v;
}

// W[co][ci][3][3] fp32 -> A[co][t*256+ci] bf16, stacked AL (Wqs,Wks,Wvs,Wqc), AV (Wkc,Wvc)
struct W6 { const float* w[6]; };
__global__ void repack_w3(W6 wp, __bf16* __restrict__ AL, __bf16* __restrict__ AV) {
  int zi = blockIdx.y;
  int e = blockIdx.x * 256 + threadIdx.x;
  int co = e / 2304;
  int rem = e - co * 2304;
  int t = rem >> 8, ci = rem & 255;
  float v = wp.w[zi][(long)co * 2304 + ci * 9 + t];
  __bf16* dst = (zi < 4) ? (AL + (long)zi * 256 * 2304) : (AV + (long)(zi - 4) * 256 * 2304);
  dst[(long)co * 2304 + rem] = (__bf16)v;
}

// ---------------------------------------------------------------------------
extern "C" void kernel_launch(void* const* d_in, const int* in_sizes, int n_in,
                              void* d_out, int out_size, void* d_ws, size_t ws_size,
                              hipStream_t stream) {
  const float* Fl  = (const float*)d_in[0];
  const float* Fv  = (const float*)d_in[1];
  const float* Wqs = (const float*)d_in[2];  const float* bqs = (const float*)d_in[3];
  const float* Wks = (const float*)d_in[4];  const float* bks = (const float*)d_in[5];
  const float* Wvs = (const float*)d_in[6];  const float* bvs = (const float*)d_in[7];
  const float* Wqc = (const float*)d_in[8];  const float* bqc = (const float*)d_in[9];
  const float* Wkc = (const float*)d_in[10]; const float* bkc = (const float*)d_in[11];
  const float* Wvc = (const float*)d_in[12]; const float* bvc = (const float*)d_in[13];
  const float* Wgs = (const float*)d_in[14]; const float* bgs = (const float*)d_in[15];
  const float* Wfu = (const float*)d_in[16]; const float* bfu = (const float*)d_in[17];

  char* ws = (char*)d_ws;
  size_t off = 0;
  auto take = [&](size_t bytes) -> void* {
    void* p = ws + off; off = (off + bytes + 255) & ~(size_t)255; return p;
  };
  __bf16* QST  = (__bf16*)take(4194304);   // Qs^T  [b][4096][256]
  __bf16* KST  = (__bf16*)take(4194304);
  __bf16* QCT  = (__bf16*)take(4194304);
  __bf16* KCT  = (__bf16*)take(4194304);
  __bf16* VS   = (__bf16*)take(4194304);   // Vs    [b][256][4096]
  __bf16* VC   = (__bf16*)take(4194304);
  __bf16* GTS  = (__bf16*)take(8388608);   // G (reshape layout) [br*2+z][4096][256]
  __bf16* AL   = (__bf16*)take(4718592);   // conv weights [1024][2304]
  __bf16* AV   = (__bf16*)take(2359296);   // [512][2304]
  __bf16* WT   = (__bf16*)take(524288);    // folded tail weights [256][1024]
  float*  BT   = (float*)take(1024);       // folded tail bias [256]
  float*  MST  = (float*)take(65536);      // [br*2+z][4096]
  float*  LST  = (float*)take(65536);
  __bf16* Xt   = (__bf16*)take(8388608);   // [img][4096][256] — alive through tail
  size_t ovl = off;                        // overlay: Cc (conv) / GACC (attn)
  __bf16* Cc = (__bf16*)take(75497472);
  size_t needConv = off;
  float* GACC = (float*)(ws + ovl);        // [2 qh][4 zbr][4096*256] fp32 = 32 MB
  size_t needAttn = ovl + 33554432;
  size_t need = needConv > needAttn ? needConv : needAttn;
  if (ws_size < need) return;

  transpose_cvt<<<dim3(128, 8, 4), dim3(32, 8), 0, stream>>>(Fl, Fv, Xt);
  im2col_k<<<dim3(4608, 4), 256, 0, stream>>>(Xt, Cc);
  W6 wp; wp.w[0]=Wqs; wp.w[1]=Wks; wp.w[2]=Wvs; wp.w[3]=Wqc; wp.w[4]=Wkc; wp.w[5]=Wvc;
  repack_w3<<<dim3(2304, 6), 256, 0, stream>>>(wp, AL, AV);
  wcomb<<<dim3(256), 256, 0, stream>>>(Wgs, bgs, Wfu, bfu, WT, BT);

  gemm_conv<<<dim3(32, 12, 2), 256, 0, stream>>>(
      AL, AV, Cc, QST, KST, VS, QCT, KCT, VC,
      bqs, bks, bvs, bqc, bkc, bvc);

  qk_stats<<<dim3(256), 256, 0, stream>>>(QST, QCT, KST, KCT, MST, LST);

  fused_pv<<<dim3(512), 256, 0, stream>>>(
      QST, QCT, KST, KCT, VS, VC, MST, LST, GACC);

  gsum_reshape<<<dim3(4, 16, 4), 256, 0, stream>>>(GACC, GTS);

  tail_gemm<<<dim3(32, 2, 2), 256, 0, stream>>>(WT, GTS, Xt, BT, (float*)d_out);
}

// Round 8
// 467.064 us; speedup vs baseline: 1.1279x; 1.0006x over previous
//
#include <hip/hip_runtime.h>

typedef __bf16 bf16x4 __attribute__((ext_vector_type(4)));
typedef __bf16 bf16x8 __attribute__((ext_vector_type(8)));
typedef float  f32x4  __attribute__((ext_vector_type(4)));

#define HWSZ 4096
#define CCH  256
#define LOG2E 1.44269504088896340736f

__device__ __forceinline__ float exp2_fast(float x) {
#if __has_builtin(__builtin_amdgcn_exp2f)
  return __builtin_amdgcn_exp2f(x);
#else
  return exp2f(x);
#endif
}

// stage 16B per lane into LDS; lane's data lands at lds_base + lane*16B
__device__ __forceinline__ void stage16(const __bf16* g, __bf16* ldsBase) {
#if __has_builtin(__builtin_amdgcn_global_load_lds)
  __builtin_amdgcn_global_load_lds(
      (const __attribute__((address_space(1))) void*)g,
      (__attribute__((address_space(3))) void*)ldsBase, 16, 0, 0);
#else
  int lane = threadIdx.x & 63;
  *(bf16x8*)(ldsBase + lane * 8) = *(const bf16x8*)g;
#endif
}

// ---------------------------------------------------------------------------
// Merged conv3x3 GEMM (128x128x32 MFMA): by<8 -> A=AL (Qs,Ks,Vs,Qc from Fl),
// else A=AV (Kc,Vc from Fv). B = im2col Cc [img][4096][2304].
// ---------------------------------------------------------------------------
__global__ __launch_bounds__(256)
void gemm_conv(const __bf16* __restrict__ AL, const __bf16* __restrict__ AV,
               const __bf16* __restrict__ Cc,
               __bf16* __restrict__ qst, __bf16* __restrict__ kst,
               __bf16* __restrict__ vs,  __bf16* __restrict__ qct,
               __bf16* __restrict__ kct, __bf16* __restrict__ vc,
               const float* __restrict__ bqs, const float* __restrict__ bks,
               const float* __restrict__ bvs, const float* __restrict__ bqc,
               const float* __restrict__ bkc, const float* __restrict__ bvc)
{
  __shared__ __align__(16) __bf16 smem[8192];
  __bf16* As = smem;
  __bf16* Bs = smem + 4096;

  const int tid  = threadIdx.x;
  const int lane = tid & 63;
  const int w    = tid >> 6;
  const int wm   = (w >> 1) * 64;
  const int wn   = (w & 1) * 64;
  const int z    = blockIdx.z;
  const int by   = blockIdx.y;
  const int bn   = blockIdx.x * 128;
  const int K    = 2304;

  const bool isL = (by < 8);
  const int bm = (isL ? by : by - 8) * 128;
  const __bf16* Ab = isL ? AL : AV;
  const __bf16* Bb = Cc + (long)((isL ? 0 : 2) + z) * 9437184;

  f32x4 acc[4][4] = {};
  const int srow = lane >> 2;
  const int skc  = (lane & 3) * 8;

  for (int k0 = 0; k0 < K; k0 += 32) {
#pragma unroll
    for (int j = 0; j < 2; ++j) {
      int rbase = w * 32 + j * 16;
      stage16(Ab + (long)(bm + rbase + srow) * K + k0 + skc, As + rbase * 32);
    }
#pragma unroll
    for (int j = 0; j < 2; ++j) {
      int rbase = w * 32 + j * 16;
      stage16(Bb + (long)(bn + rbase + srow) * K + k0 + skc, Bs + rbase * 32);
    }
    __syncthreads();
    bf16x8 af[4], bfr[4];
#pragma unroll
    for (int t = 0; t < 4; ++t)
      af[t] = *(const bf16x8*)(As + (wm + t * 16 + (lane & 15)) * 32 + (lane >> 4) * 8);
#pragma unroll
    for (int t = 0; t < 4; ++t)
      bfr[t] = *(const bf16x8*)(Bs + (wn + t * 16 + (lane & 15)) * 32 + (lane >> 4) * 8);
#pragma unroll
    for (int mt = 0; mt < 4; ++mt)
#pragma unroll
      for (int nt = 0; nt < 4; ++nt)
        acc[mt][nt] = __builtin_amdgcn_mfma_f32_16x16x32_bf16(af[mt], bfr[nt], acc[mt][nt], 0, 0, 0);
    __syncthreads();
  }

#pragma unroll
  for (int mt = 0; mt < 4; ++mt) {
#pragma unroll
    for (int nt = 0; nt < 4; ++nt) {
#pragma unroll
      for (int r = 0; r < 4; ++r) {
        int m = bm + wm + mt * 16 + (lane >> 4) * 4 + r;
        int n = bn + wn + nt * 16 + (lane & 15);
        int g = m >> 8, mm = m & 255;
        const float* bias; __bf16* op; bool vlay;
        if (isL) {
          bias = (g == 0) ? bqs : (g == 1) ? bks : (g == 2) ? bvs : bqc;
          op   = (g == 0) ? qst : (g == 1) ? kst : (g == 2) ? vs  : qct;
          vlay = (g == 2);
        } else {
          bias = g ? bvc : bkc;
          op   = g ? vc  : kct;
          vlay = (g == 1);
        }
        float vv = acc[mt][nt][r] + bias[mm];
        if (vlay) op[(long)z * 1048576 + (long)mm * HWSZ + n] = (__bf16)vv;   // V: [c,p]
        else      op[(long)z * 1048576 + (long)n * CCH + mm] = (__bf16)vv;    // Q/K: [p,c]
      }
    }
  }
}

// ---------------------------------------------------------------------------
// qk_stats: full column-softmax stats (max/sumexp over i, per q).
// 1-D grid 256 blocks, XCD-swizzled: group g = lid&3 -> (z, br); qb = lid>>2.
// ---------------------------------------------------------------------------
__global__ __launch_bounds__(256)
void qk_stats(const __bf16* __restrict__ qs, const __bf16* __restrict__ qc,
              const __bf16* __restrict__ ks, const __bf16* __restrict__ kc,
              float* __restrict__ mst, float* __restrict__ lst)
{
  __shared__ __align__(16) __bf16 Kres[64 * 260];
  __shared__ float wm_[4][64], wl_[4][64];

  const int tid = threadIdx.x, lane = tid & 63, w = tid >> 6;
  const int quad = lane >> 4, l15 = lane & 15;
  const int lid = blockIdx.x;
  const int g = lid & 3;
  const int z = g & 1, br = g >> 1;
  const int qb = (lid >> 2) * 64;
  const __bf16* Qt = (br ? qc : qs) + (long)z * 1048576;
  const __bf16* Kt = (br ? kc : ks) + (long)z * 1048576;

  for (int idx = tid; idx < 2048; idx += 256) {
    int r = idx >> 5, c8 = (idx & 31) * 8;
    *(bf16x8*)(Kres + r * 260 + c8) = *(const bf16x8*)(Kt + (long)(qb + r) * 256 + c8);
  }
  __syncthreads();

  float rm[4], rl[4];
#pragma unroll
  for (int nt = 0; nt < 4; ++nt) { rm[nt] = -3.0e38f; rl[nt] = 0.f; }

  for (int it = 0; it < 16; ++it) {
    const int i0 = it * 256 + w * 64;
    f32x4 accS[4][4] = {};
#pragma unroll
    for (int cs = 0; cs < 256; cs += 32) {
      bf16x8 a[4], b[4];
#pragma unroll
      for (int mt = 0; mt < 4; ++mt)
        a[mt] = *(const bf16x8*)(Qt + (long)(i0 + mt * 16 + l15) * 256 + cs + quad * 8);
#pragma unroll
      for (int nt = 0; nt < 4; ++nt)
        b[nt] = *(const bf16x8*)(Kres + (nt * 16 + l15) * 260 + cs + quad * 8);
#pragma unroll
      for (int mt = 0; mt < 4; ++mt)
#pragma unroll
        for (int nt = 0; nt < 4; ++nt)
          accS[mt][nt] = __builtin_amdgcn_mfma_f32_16x16x32_bf16(a[mt], b[nt], accS[mt][nt], 0, 0, 0);
    }
#pragma unroll
    for (int nt = 0; nt < 4; ++nt) {
      float mx = -3.0e38f;
#pragma unroll
      for (int mt = 0; mt < 4; ++mt)
#pragma unroll
        for (int r = 0; r < 4; ++r) mx = fmaxf(mx, accS[mt][nt][r]);
      float sl = 0.f;
#pragma unroll
      for (int mt = 0; mt < 4; ++mt)
#pragma unroll
        for (int r = 0; r < 4; ++r) sl += exp2_fast((accS[mt][nt][r] - mx) * LOG2E);
#pragma unroll
      for (int d = 16; d <= 32; d <<= 1) {
        float om = __shfl_xor(mx, d, 64);
        float ol = __shfl_xor(sl, d, 64);
        float nm = fmaxf(mx, om);
        sl = sl * exp2_fast((mx - nm) * LOG2E) + ol * exp2_fast((om - nm) * LOG2E);
        mx = nm;
      }
      float nm = fmaxf(rm[nt], mx);
      rl[nt] = rl[nt] * exp2_fast((rm[nt] - nm) * LOG2E) + sl * exp2_fast((mx - nm) * LOG2E);
      rm[nt] = nm;
    }
  }
  if (lane < 16) {
#pragma unroll
    for (int nt = 0; nt < 4; ++nt) { wm_[w][nt * 16 + lane] = rm[nt]; wl_[w][nt * 16 + lane] = rl[nt]; }
  }
  __syncthreads();
  if (tid < 64) {
    float m = -3.0e38f;
#pragma unroll
    for (int ww = 0; ww < 4; ++ww) m = fmaxf(m, wm_[ww][tid]);
    float l = 0.f;
#pragma unroll
    for (int ww = 0; ww < 4; ++ww)
      l += wl_[ww][tid] * exp2_fast((wm_[ww][tid] - m) * LOG2E);
    long o = ((long)(br * 2 + z)) * 4096 + qb + tid;
    mst[o] = m;
    lst[o] = 1.0f / l;
  }
}

// ---------------------------------------------------------------------------
// Fused recompute-S PV, round-8 structure:
// - Q A-fragments in REGISTERS (wave owns 16 i-rows; 8 bf16x8 = 32 VGPR,
//   loaded once per block) -> no Qres LDS, no Qres ds_reads.
// - K staged via global_load_lds with DOUBLE BUFFER: 1 barrier per 32-col
//   chunk (was 2). 10 barriers per 128-q tile total (was 17).
// - V direct global->reg (independent, hoistable). LDS 33 KB.
// 1-D grid 512, XCD-swizzled: g = lid&7 -> (zbr = g>>1, qh = g&1).
// ---------------------------------------------------------------------------
__global__ __launch_bounds__(256)
void fused_pv(const __bf16* __restrict__ qs, const __bf16* __restrict__ qc,
              const __bf16* __restrict__ ks, const __bf16* __restrict__ kc,
              const __bf16* __restrict__ vs, const __bf16* __restrict__ vc,
              const float* __restrict__ mst, const float* __restrict__ lst,
              float* __restrict__ gacc)
{
  __shared__ __align__(16) __bf16 Kst[2][128 * 32];  // 16 KB (double buffer)
  __shared__ __align__(16) __bf16 Pl[64 * 132];      // 16.9 KB

  const int tid = threadIdx.x, lane = tid & 63, w = tid >> 6;
  const int quad = lane >> 4, l15 = lane & 15;
  const int lid = blockIdx.x;
  const int g   = lid & 7;
  const int zbr = g >> 1;
  const int qh  = g & 1;
  const int bi  = (lid >> 3) * 64;
  const int br = zbr >> 1, z = zbr & 1;
  const __bf16* Qt = (br ? qc : qs) + (long)z * 1048576;
  const __bf16* Kt = (br ? kc : ks) + (long)z * 1048576;
  const __bf16* Vv = (br ? vc : vs) + (long)z * 1048576;
  const float* msp = mst + (long)zbr * 4096;
  const float* lsp = lst + (long)zbr * 4096;
  float* go = gacc + ((long)qh * 4 + zbr) * 1048576;

  // Q preload: wave w owns i-rows [bi + w*16, +16); A-frag per 32-col chunk
  bf16x8 aqr[8];
#pragma unroll
  for (int c8 = 0; c8 < 8; ++c8)
    aqr[c8] = *(const bf16x8*)(Qt + (long)(bi + w * 16 + l15) * 256 + c8 * 32 + quad * 8);

  f32x4 accO[4][4] = {};
  const int srow = lane >> 2, skc = (lane & 3) * 8;
  const int q0 = qh * 2048;

  for (int qt = 0; qt < 16; ++qt) {
    const int qc0 = q0 + qt * 128;
    // stage K chunk 0 into buf 0
#pragma unroll
    for (int jj = 0; jj < 2; ++jj) {
      int rbase = w * 32 + jj * 16;
      stage16(Kt + (long)(qc0 + rbase + srow) * 256 + skc, Kst[0] + rbase * 32);
    }
    __syncthreads();
    // --- S phase: dbuf K, 1 barrier per chunk ---
    f32x4 accS[8] = {};
#pragma unroll
    for (int cs = 0; cs < 8; ++cs) {
      if (cs < 7) {
#pragma unroll
        for (int jj = 0; jj < 2; ++jj) {
          int rbase = w * 32 + jj * 16;
          stage16(Kt + (long)(qc0 + rbase + srow) * 256 + (cs + 1) * 32 + skc,
                  Kst[(cs + 1) & 1] + rbase * 32);
        }
      }
      const __bf16* kb = Kst[cs & 1];
#pragma unroll
      for (int nt = 0; nt < 8; ++nt) {
        bf16x8 bk = *(const bf16x8*)(kb + (nt * 16 + l15) * 32 + quad * 8);
        accS[nt] = __builtin_amdgcn_mfma_f32_16x16x32_bf16(aqr[cs], bk, accS[nt], 0, 0, 0);
      }
      __syncthreads();   // buf reuse + next-stage visibility
    }
    // P = exp(S - m_q)*linv_q -> Pl (wave w writes its own 16 i-rows)
#pragma unroll
    for (int nt = 0; nt < 8; ++nt) {
      int q = nt * 16 + l15;
      float mq = msp[qc0 + q], lq = lsp[qc0 + q];
#pragma unroll
      for (int r = 0; r < 4; ++r) {
        int i = w * 16 + quad * 4 + r;
        Pl[i * 132 + q] = (__bf16)(exp2_fast((accS[nt][r] - mq) * LOG2E) * lq);
      }
    }
    __syncthreads();
    // --- V phase: direct-reg V, no barriers ---
#pragma unroll
    for (int qs0 = 0; qs0 < 128; qs0 += 32) {
      bf16x8 ap[4], bv[4];
#pragma unroll
      for (int mt = 0; mt < 4; ++mt)
        ap[mt] = *(const bf16x8*)(Pl + (mt * 16 + l15) * 132 + qs0 + quad * 8);
#pragma unroll
      for (int nt = 0; nt < 4; ++nt)
        bv[nt] = *(const bf16x8*)(Vv + (long)(w * 64 + nt * 16 + l15) * 4096 + qc0 + qs0 + quad * 8);
#pragma unroll
      for (int mt = 0; mt < 4; ++mt)
#pragma unroll
        for (int nt = 0; nt < 4; ++nt)
          accO[mt][nt] = __builtin_amdgcn_mfma_f32_16x16x32_bf16(ap[mt], bv[nt], accO[mt][nt], 0, 0, 0);
    }
  }
  // natural-layout fp32 partial store (coalesced 64B segments)
#pragma unroll
  for (int mt = 0; mt < 4; ++mt)
#pragma unroll
    for (int nt = 0; nt < 4; ++nt)
#pragma unroll
      for (int r = 0; r < 4; ++r) {
        int i = mt * 16 + quad * 4 + r;
        int j = w * 64 + nt * 16 + l15;
        go[(long)(bi + i) * 256 + j] = accO[mt][nt][r];
      }
}

// ---------------------------------------------------------------------------
// Sum the two q-half partials and write GTS in raw-reshape layout via LDS
// transpose. grid (jg 4, v 16, zbr 4), 256 threads.
__global__ __launch_bounds__(256)
void gsum_reshape(const float* __restrict__ ga, __bf16* __restrict__ gt) {
  __shared__ __bf16 lds[64 * 260];
  const int t = threadIdx.x, lane = t & 63, w = t >> 6;
  const int zbr = blockIdx.z;
  const int v   = blockIdx.y;
  const int jg  = blockIdx.x;
  const float* g0 = ga + (long)zbr * 1048576;
  const float* g1 = g0 + 4194304;
  for (int ci0 = 0; ci0 < 256; ci0 += 4) {
    int ci = ci0 + w;
    long src = (long)(ci * 16 + v) * 256 + jg * 64 + lane;
    lds[lane * 260 + ci] = (__bf16)(g0[src] + g1[src]);
  }
  __syncthreads();
  __bf16* out = gt + (long)zbr * 1048576 + ((long)v * 256 + jg * 64) * 256;
#pragma unroll
  for (int pp = 0; pp < 8; ++pp) {
    int idx = pp * 256 + t;
    int row = idx >> 5, c8 = (idx & 31) * 8;
    *(bf16x8*)(out + (long)row * 256 + c8) = *(const bf16x8*)(lds + row * 260 + c8);
  }
}

// ---------------------------------------------------------------------------
// Weight fold: WT = [Wfu_l*Wgs | Wfu_v*Wgs | Wfu_l | Wfu_v] (bf16 [256][1024]),
// biasT[co] = bfu[co] + sum_c (Wfu[co][c]+Wfu[co][c+256]) * bgs[c].
__global__ __launch_bounds__(256)
void wcomb(const float* __restrict__ Wgs, const float* __restrict__ bgs,
           const float* __restrict__ Wfu, const float* __restrict__ bfu,
           __bf16* __restrict__ WT, float* __restrict__ biasT)
{
  const int co = blockIdx.x, t = threadIdx.x;
  const float* wrow = Wfu + (long)co * 512;
  float accs = 0.f, accc = 0.f;
  for (int c = 0; c < 256; ++c) {
    float gv = Wgs[(long)c * 256 + t];
    accs = fmaf(wrow[c], gv, accs);
    accc = fmaf(wrow[c + 256], gv, accc);
  }
  __bf16* o = WT + (long)co * 1024;
  o[t]       = (__bf16)accs;
  o[256 + t] = (__bf16)accc;
  o[512 + t] = (__bf16)wrow[t];
  o[768 + t] = (__bf16)wrow[256 + t];
  __shared__ float red[256];
  red[t] = (wrow[t] + wrow[t + 256]) * bgs[t];
  __syncthreads();
  for (int s = 128; s > 0; s >>= 1) {
    if (t < s) red[t] += red[t + s];
    __syncthreads();
  }
  if (t == 0) biasT[co] = bfu[co] + red[0];
}

// ---------------------------------------------------------------------------
// Tail GEMM: out[z][co][p] = sum_k WT[co][k] * Bcat[z][p][k] + biasT[co],
// Bcat k-groups: 0 GTS_s, 1 GTS_c, 2 Xt(Fl), 3 Xt(Fv). grid (32, 2, 2).
__global__ __launch_bounds__(256)
void tail_gemm(const __bf16* __restrict__ WT, const __bf16* __restrict__ GTS,
               const __bf16* __restrict__ Xt, const float* __restrict__ biasT,
               float* __restrict__ out)
{
  __shared__ __align__(16) __bf16 smem[8192];
  __bf16* As = smem;
  __bf16* Bs = smem + 4096;

  const int tid  = threadIdx.x;
  const int lane = tid & 63;
  const int w    = tid >> 6;
  const int wm   = (w >> 1) * 64;
  const int wn   = (w & 1) * 64;
  const int z    = blockIdx.z;
  const int bm   = blockIdx.y * 128;
  const int bn   = blockIdx.x * 128;

  const __bf16* Bsel[4] = {
    GTS + (long)z * 1048576, GTS + (long)(2 + z) * 1048576,
    Xt  + (long)z * 1048576, Xt  + (long)(2 + z) * 1048576
  };

  f32x4 acc[4][4] = {};
  const int srow = lane >> 2;
  const int skc  = (lane & 3) * 8;

  for (int k0 = 0; k0 < 1024; k0 += 32) {
    const __bf16* Bb = Bsel[k0 >> 8];
    const int kk = k0 & 255;
#pragma unroll
    for (int j = 0; j < 2; ++j) {
      int rbase = w * 32 + j * 16;
      stage16(WT + (long)(bm + rbase + srow) * 1024 + k0 + skc, As + rbase * 32);
    }
#pragma unroll
    for (int j = 0; j < 2; ++j) {
      int rbase = w * 32 + j * 16;
      stage16(Bb + (long)(bn + rbase + srow) * 256 + kk + skc, Bs + rbase * 32);
    }
    __syncthreads();
    bf16x8 af[4], bfr[4];
#pragma unroll
    for (int t = 0; t < 4; ++t)
      af[t] = *(const bf16x8*)(As + (wm + t * 16 + (lane & 15)) * 32 + (lane >> 4) * 8);
#pragma unroll
    for (int t = 0; t < 4; ++t)
      bfr[t] = *(const bf16x8*)(Bs + (wn + t * 16 + (lane & 15)) * 32 + (lane >> 4) * 8);
#pragma unroll
    for (int mt = 0; mt < 4; ++mt)
#pragma unroll
      for (int nt = 0; nt < 4; ++nt)
        acc[mt][nt] = __builtin_amdgcn_mfma_f32_16x16x32_bf16(af[mt], bfr[nt], acc[mt][nt], 0, 0, 0);
    __syncthreads();
  }

#pragma unroll
  for (int mt = 0; mt < 4; ++mt)
#pragma unroll
    for (int nt = 0; nt < 4; ++nt)
#pragma unroll
      for (int r = 0; r < 4; ++r) {
        int m = bm + wm + mt * 16 + (lane >> 4) * 4 + r;
        int n = bn + wn + nt * 16 + (lane & 15);
        out[((long)z * 256 + m) * HWSZ + n] = acc[mt][nt][r] + biasT[m];
      }
}

// ---------------------------------------------------------------------------
// Fl/Fv [b][256][4096] fp32 -> Xt [img][4096][256] bf16 (Fl b0, Fl b1, Fv b0, Fv b1)
__global__ void transpose_cvt(const float* __restrict__ F0, const float* __restrict__ F1,
                              __bf16* __restrict__ Xt) {
  __shared__ float tile[32][33];
  int img = blockIdx.z;
  const float* src = (img < 2 ? F0 : F1) + (long)(img & 1) * (CCH * HWSZ);
  __bf16* dst = Xt + (long)img * (HWSZ * CCH);
  int p0 = blockIdx.x * 32, c0 = blockIdx.y * 32;
  int tx = threadIdx.x, ty = threadIdx.y;
#pragma unroll
  for (int j = 0; j < 32; j += 8)
    tile[ty + j][tx] = src[(long)(c0 + ty + j) * HWSZ + p0 + tx];
  __syncthreads();
#pragma unroll
  for (int j = 0; j < 32; j += 8)
    dst[(long)(p0 + ty + j) * CCH + c0 + tx] = (__bf16)tile[tx][ty + j];
}

// Xt -> im2col Cc [img][4096][2304], k = t*256+ci, zero-padded borders
__global__ void im2col_k(const __bf16* __restrict__ Xt, __bf16* __restrict__ Cc) {
  int img = blockIdx.y;
  int e = blockIdx.x * 256 + threadIdx.x;
  int p = e / 288;
  int c8 = e - p * 288;
  int t = c8 >> 5;
  int ci0 = (c8 & 31) * 8;
  int dy = t / 3 - 1, dx = t - (t / 3) * 3 - 1;
  int y = p >> 6, x = p & 63;
  int yy = y + dy, xx = x + dx;
  const __bf16* src = Xt + (long)img * (HWSZ * CCH);
  __bf16* dst = Cc + (long)img * 9437184 + (long)p * 2304 + t * 256 + ci0;
  uint4 v = make_uint4(0u, 0u, 0u, 0u);
  if ((unsigned)yy < 64u && (unsigned)xx < 64u)
    v = *(const uint4*)(src + (long)(yy * 64 + xx) * CCH + ci0);
  *(uint4*)dst = v;
}

// W[co][ci][3][3] fp32 -> A[co][t*256+ci] bf16, stacked AL (Wqs,Wks,Wvs,Wqc), AV (Wkc,Wvc)
struct W6 { const float* w[6]; };
__global__ void repack_w3(W6 wp, __bf16* __restrict__ AL, __bf16* __restrict__ AV) {
  int zi = blockIdx.y;
  int e = blockIdx.x * 256 + threadIdx.x;
  int co = e / 2304;
  int rem = e - co * 2304;
  int t = rem >> 8, ci = rem & 255;
  float v = wp.w[zi][(long)co * 2304 + ci * 9 + t];
  __bf16* dst = (zi < 4) ? (AL + (long)zi * 256 * 2304) : (AV + (long)(zi - 4) * 256 * 2304);
  dst[(long)co * 2304 + rem] = (__bf16)v;
}

// ---------------------------------------------------------------------------
extern "C" void kernel_launch(void* const* d_in, const int* in_sizes, int n_in,
                              void* d_out, int out_size, void* d_ws, size_t ws_size,
                              hipStream_t stream) {
  const float* Fl  = (const float*)d_in[0];
  const float* Fv  = (const float*)d_in[1];
  const float* Wqs = (const float*)d_in[2];  const float* bqs = (const float*)d_in[3];
  const float* Wks = (const float*)d_in[4];  const float* bks = (const float*)d_in[5];
  const float* Wvs = (const float*)d_in[6];  const float* bvs = (const float*)d_in[7];
  const float* Wqc = (const float*)d_in[8];  const float* bqc = (const float*)d_in[9];
  const float* Wkc = (const float*)d_in[10]; const float* bkc = (const float*)d_in[11];
  const float* Wvc = (const float*)d_in[12]; const float* bvc = (const float*)d_in[13];
  const float* Wgs = (const float*)d_in[14]; const float* bgs = (const float*)d_in[15];
  const float* Wfu = (const float*)d_in[16]; const float* bfu = (const float*)d_in[17];

  char* ws = (char*)d_ws;
  size_t off = 0;
  auto take = [&](size_t bytes) -> void* {
    void* p = ws + off; off = (off + bytes + 255) & ~(size_t)255; return p;
  };
  __bf16* QST  = (__bf16*)take(4194304);   // Qs^T  [b][4096][256]
  __bf16* KST  = (__bf16*)take(4194304);
  __bf16* QCT  = (__bf16*)take(4194304);
  __bf16* KCT  = (__bf16*)take(4194304);
  __bf16* VS   = (__bf16*)take(4194304);   // Vs    [b][256][4096]
  __bf16* VC   = (__bf16*)take(4194304);
  __bf16* GTS  = (__bf16*)take(8388608);   // G (reshape layout) [br*2+z][4096][256]
  __bf16* AL   = (__bf16*)take(4718592);   // conv weights [1024][2304]
  __bf16* AV   = (__bf16*)take(2359296);   // [512][2304]
  __bf16* WT   = (__bf16*)take(524288);    // folded tail weights [256][1024]
  float*  BT   = (float*)take(1024);       // folded tail bias [256]
  float*  MST  = (float*)take(65536);      // [br*2+z][4096]
  float*  LST  = (float*)take(65536);
  __bf16* Xt   = (__bf16*)take(8388608);   // [img][4096][256] — alive through tail
  size_t ovl = off;                        // overlay: Cc (conv) / GACC (attn)
  __bf16* Cc = (__bf16*)take(75497472);
  size_t needConv = off;
  float* GACC = (float*)(ws + ovl);        // [2 qh][4 zbr][4096*256] fp32 = 32 MB
  size_t needAttn = ovl + 33554432;
  size_t need = needConv > needAttn ? needConv : needAttn;
  if (ws_size < need) return;

  transpose_cvt<<<dim3(128, 8, 4), dim3(32, 8), 0, stream>>>(Fl, Fv, Xt);
  im2col_k<<<dim3(4608, 4), 256, 0, stream>>>(Xt, Cc);
  W6 wp; wp.w[0]=Wqs; wp.w[1]=Wks; wp.w[2]=Wvs; wp.w[3]=Wqc; wp.w[4]=Wkc; wp.w[5]=Wvc;
  repack_w3<<<dim3(2304, 6), 256, 0, stream>>>(wp, AL, AV);
  wcomb<<<dim3(256), 256, 0, stream>>>(Wgs, bgs, Wfu, bfu, WT, BT);

  gemm_conv<<<dim3(32, 12, 2), 256, 0, stream>>>(
      AL, AV, Cc, QST, KST, VS, QCT, KCT, VC,
      bqs, bks, bvs, bqc, bkc, bvc);

  qk_stats<<<dim3(256), 256, 0, stream>>>(QST, QCT, KST, KCT, MST, LST);

  fused_pv<<<dim3(512), 256, 0, stream>>>(
      QST, QCT, KST, KCT, VS, VC, MST, LST, GACC);

  gsum_reshape<<<dim3(4, 16, 4), 256, 0, stream>>>(GACC, GTS);

  tail_gemm<<<dim3(32, 2, 2), 256, 0, stream>>>(WT, GTS, Xt, BT, (float*)d_out);
}

// Round 9
// 456.199 us; speedup vs baseline: 1.1548x; 1.0238x over previous
//
#include <hip/hip_runtime.h>

typedef __bf16 bf16x4 __attribute__((ext_vector_type(4)));
typedef __bf16 bf16x8 __attribute__((ext_vector_type(8)));
typedef float  f32x4  __attribute__((ext_vector_type(4)));

#define HWSZ 4096
#define CCH  256
#define LOG2E 1.44269504088896340736f

__device__ __forceinline__ float exp2_fast(float x) {
#if __has_builtin(__builtin_amdgcn_exp2f)
  return __builtin_amdgcn_exp2f(x);
#else
  return exp2f(x);
#endif
}

// stage 16B per lane into LDS; lane's data lands at lds_base + lane*16B
__device__ __forceinline__ void stage16(const __bf16* g, __bf16* ldsBase) {
#if __has_builtin(__builtin_amdgcn_global_load_lds)
  __builtin_amdgcn_global_load_lds(
      (const __attribute__((address_space(1))) void*)g,
      (__attribute__((address_space(3))) void*)ldsBase, 16, 0, 0);
#else
  int lane = threadIdx.x & 63;
  *(bf16x8*)(ldsBase + lane * 8) = *(const bf16x8*)g;
#endif
}

// ---------------------------------------------------------------------------
// Merged conv3x3 GEMM (128x128x32 MFMA): by<8 -> A=AL (Qs,Ks,Vs,Qc from Fl),
// else A=AV (Kc,Vc from Fv). B = im2col Cc [img][4096][2304].
// ---------------------------------------------------------------------------
__global__ __launch_bounds__(256)
void gemm_conv(const __bf16* __restrict__ AL, const __bf16* __restrict__ AV,
               const __bf16* __restrict__ Cc,
               __bf16* __restrict__ qst, __bf16* __restrict__ kst,
               __bf16* __restrict__ vs,  __bf16* __restrict__ qct,
               __bf16* __restrict__ kct, __bf16* __restrict__ vc,
               const float* __restrict__ bqs, const float* __restrict__ bks,
               const float* __restrict__ bvs, const float* __restrict__ bqc,
               const float* __restrict__ bkc, const float* __restrict__ bvc)
{
  __shared__ __align__(16) __bf16 smem[8192];
  __bf16* As = smem;
  __bf16* Bs = smem + 4096;

  const int tid  = threadIdx.x;
  const int lane = tid & 63;
  const int w    = tid >> 6;
  const int wm   = (w >> 1) * 64;
  const int wn   = (w & 1) * 64;
  const int z    = blockIdx.z;
  const int by   = blockIdx.y;
  const int bn   = blockIdx.x * 128;
  const int K    = 2304;

  const bool isL = (by < 8);
  const int bm = (isL ? by : by - 8) * 128;
  const __bf16* Ab = isL ? AL : AV;
  const __bf16* Bb = Cc + (long)((isL ? 0 : 2) + z) * 9437184;

  f32x4 acc[4][4] = {};
  const int srow = lane >> 2;
  const int skc  = (lane & 3) * 8;

  for (int k0 = 0; k0 < K; k0 += 32) {
#pragma unroll
    for (int j = 0; j < 2; ++j) {
      int rbase = w * 32 + j * 16;
      stage16(Ab + (long)(bm + rbase + srow) * K + k0 + skc, As + rbase * 32);
    }
#pragma unroll
    for (int j = 0; j < 2; ++j) {
      int rbase = w * 32 + j * 16;
      stage16(Bb + (long)(bn + rbase + srow) * K + k0 + skc, Bs + rbase * 32);
    }
    __syncthreads();
    bf16x8 af[4], bfr[4];
#pragma unroll
    for (int t = 0; t < 4; ++t)
      af[t] = *(const bf16x8*)(As + (wm + t * 16 + (lane & 15)) * 32 + (lane >> 4) * 8);
#pragma unroll
    for (int t = 0; t < 4; ++t)
      bfr[t] = *(const bf16x8*)(Bs + (wn + t * 16 + (lane & 15)) * 32 + (lane >> 4) * 8);
#pragma unroll
    for (int mt = 0; mt < 4; ++mt)
#pragma unroll
      for (int nt = 0; nt < 4; ++nt)
        acc[mt][nt] = __builtin_amdgcn_mfma_f32_16x16x32_bf16(af[mt], bfr[nt], acc[mt][nt], 0, 0, 0);
    __syncthreads();
  }

#pragma unroll
  for (int mt = 0; mt < 4; ++mt) {
#pragma unroll
    for (int nt = 0; nt < 4; ++nt) {
#pragma unroll
      for (int r = 0; r < 4; ++r) {
        int m = bm + wm + mt * 16 + (lane >> 4) * 4 + r;
        int n = bn + wn + nt * 16 + (lane & 15);
        int g = m >> 8, mm = m & 255;
        const float* bias; __bf16* op; bool vlay;
        if (isL) {
          bias = (g == 0) ? bqs : (g == 1) ? bks : (g == 2) ? bvs : bqc;
          op   = (g == 0) ? qst : (g == 1) ? kst : (g == 2) ? vs  : qct;
          vlay = (g == 2);
        } else {
          bias = g ? bvc : bkc;
          op   = g ? vc  : kct;
          vlay = (g == 1);
        }
        float vv = acc[mt][nt][r] + bias[mm];
        if (vlay) op[(long)z * 1048576 + (long)mm * HWSZ + n] = (__bf16)vv;   // V: [c,p]
        else      op[(long)z * 1048576 + (long)n * CCH + mm] = (__bf16)vv;    // Q/K: [p,c]
      }
    }
  }
}

// ---------------------------------------------------------------------------
// qk_stats: partial column-softmax stats over HALF the i-range.
// 1-D grid 512: lid = qbIdx*8 + ih*4 + g, g -> (z, br). Writes pm/pl
// [ih][br*2+z][4096]; combined by stats_combine2.
// ---------------------------------------------------------------------------
__global__ __launch_bounds__(256)
void qk_stats(const __bf16* __restrict__ qs, const __bf16* __restrict__ qc,
              const __bf16* __restrict__ ks, const __bf16* __restrict__ kc,
              float* __restrict__ pm, float* __restrict__ pl)
{
  __shared__ __align__(16) __bf16 Kres[64 * 260];
  __shared__ float wm_[4][64], wl_[4][64];

  const int tid = threadIdx.x, lane = tid & 63, w = tid >> 6;
  const int quad = lane >> 4, l15 = lane & 15;
  const int lid = blockIdx.x;
  const int g = lid & 3;
  const int z = g & 1, br = g >> 1;
  const int ih = (lid >> 2) & 1;
  const int qb = (lid >> 3) * 64;
  const __bf16* Qt = (br ? qc : qs) + (long)z * 1048576;
  const __bf16* Kt = (br ? kc : ks) + (long)z * 1048576;

  for (int idx = tid; idx < 2048; idx += 256) {
    int r = idx >> 5, c8 = (idx & 31) * 8;
    *(bf16x8*)(Kres + r * 260 + c8) = *(const bf16x8*)(Kt + (long)(qb + r) * 256 + c8);
  }
  __syncthreads();

  float rm[4], rl[4];
#pragma unroll
  for (int nt = 0; nt < 4; ++nt) { rm[nt] = -3.0e38f; rl[nt] = 0.f; }

  for (int it = 0; it < 8; ++it) {
    const int i0 = ih * 2048 + it * 256 + w * 64;
    f32x4 accS[4][4] = {};
#pragma unroll
    for (int cs = 0; cs < 256; cs += 32) {
      bf16x8 a[4], b[4];
#pragma unroll
      for (int mt = 0; mt < 4; ++mt)
        a[mt] = *(const bf16x8*)(Qt + (long)(i0 + mt * 16 + l15) * 256 + cs + quad * 8);
#pragma unroll
      for (int nt = 0; nt < 4; ++nt)
        b[nt] = *(const bf16x8*)(Kres + (nt * 16 + l15) * 260 + cs + quad * 8);
#pragma unroll
      for (int mt = 0; mt < 4; ++mt)
#pragma unroll
        for (int nt = 0; nt < 4; ++nt)
          accS[mt][nt] = __builtin_amdgcn_mfma_f32_16x16x32_bf16(a[mt], b[nt], accS[mt][nt], 0, 0, 0);
    }
#pragma unroll
    for (int nt = 0; nt < 4; ++nt) {
      float mx = -3.0e38f;
#pragma unroll
      for (int mt = 0; mt < 4; ++mt)
#pragma unroll
        for (int r = 0; r < 4; ++r) mx = fmaxf(mx, accS[mt][nt][r]);
      float sl = 0.f;
#pragma unroll
      for (int mt = 0; mt < 4; ++mt)
#pragma unroll
        for (int r = 0; r < 4; ++r) sl += exp2_fast((accS[mt][nt][r] - mx) * LOG2E);
#pragma unroll
      for (int d = 16; d <= 32; d <<= 1) {
        float om = __shfl_xor(mx, d, 64);
        float ol = __shfl_xor(sl, d, 64);
        float nm = fmaxf(mx, om);
        sl = sl * exp2_fast((mx - nm) * LOG2E) + ol * exp2_fast((om - nm) * LOG2E);
        mx = nm;
      }
      float nm = fmaxf(rm[nt], mx);
      rl[nt] = rl[nt] * exp2_fast((rm[nt] - nm) * LOG2E) + sl * exp2_fast((mx - nm) * LOG2E);
      rm[nt] = nm;
    }
  }
  if (lane < 16) {
#pragma unroll
    for (int nt = 0; nt < 4; ++nt) { wm_[w][nt * 16 + lane] = rm[nt]; wl_[w][nt * 16 + lane] = rl[nt]; }
  }
  __syncthreads();
  if (tid < 64) {
    float m = -3.0e38f;
#pragma unroll
    for (int ww = 0; ww < 4; ++ww) m = fmaxf(m, wm_[ww][tid]);
    float l = 0.f;
#pragma unroll
    for (int ww = 0; ww < 4; ++ww)
      l += wl_[ww][tid] * exp2_fast((wm_[ww][tid] - m) * LOG2E);
    long o = ((long)ih * 4 + br * 2 + z) * 4096 + qb + tid;
    pm[o] = m;
    pl[o] = l;
  }
}

// combine the two i-half partials -> final m, 1/l. grid (16, 4 zbr), 256 thr.
__global__ void stats_combine2(const float* __restrict__ pm, const float* __restrict__ pl,
                               float* __restrict__ mst, float* __restrict__ lst) {
  int q = blockIdx.x * 256 + threadIdx.x;
  int zbr = blockIdx.y;
  float m0 = pm[(long)zbr * 4096 + q],        l0 = pl[(long)zbr * 4096 + q];
  float m1 = pm[(long)(4 + zbr) * 4096 + q],  l1 = pl[(long)(4 + zbr) * 4096 + q];
  float m = fmaxf(m0, m1);
  float l = l0 * exp2_fast((m0 - m) * LOG2E) + l1 * exp2_fast((m1 - m) * LOG2E);
  mst[(long)zbr * 4096 + q] = m;
  lst[(long)zbr * 4096 + q] = 1.0f / l;
}

// ---------------------------------------------------------------------------
// Fused recompute-S PV (round-9): grid 1024 = 64 i-blocks x 16 groups
// (zbr, q-quarter) -> 4 blocks/CU. Q A-frags in registers; K staged via
// global_load_lds double-buffer (1 barrier/chunk); V direct global->reg.
// fp32 partials per q-quarter in natural [i][j] layout.
// ---------------------------------------------------------------------------
__global__ __launch_bounds__(256)
void fused_pv(const __bf16* __restrict__ qs, const __bf16* __restrict__ qc,
              const __bf16* __restrict__ ks, const __bf16* __restrict__ kc,
              const __bf16* __restrict__ vs, const __bf16* __restrict__ vc,
              const float* __restrict__ mst, const float* __restrict__ lst,
              float* __restrict__ gacc)
{
  __shared__ __align__(16) __bf16 Kst[2][128 * 32];  // 16 KB (double buffer)
  __shared__ __align__(16) __bf16 Pl[64 * 132];      // 16.9 KB

  const int tid = threadIdx.x, lane = tid & 63, w = tid >> 6;
  const int quad = lane >> 4, l15 = lane & 15;
  const int lid = blockIdx.x;
  const int g   = lid & 15;
  const int zbr = g >> 2;
  const int qq  = g & 3;
  const int bi  = (lid >> 4) * 64;
  const int br = zbr >> 1, z = zbr & 1;
  const __bf16* Qt = (br ? qc : qs) + (long)z * 1048576;
  const __bf16* Kt = (br ? kc : ks) + (long)z * 1048576;
  const __bf16* Vv = (br ? vc : vs) + (long)z * 1048576;
  const float* msp = mst + (long)zbr * 4096;
  const float* lsp = lst + (long)zbr * 4096;
  float* go = gacc + ((long)qq * 4 + zbr) * 1048576;

  // Q preload: wave w owns i-rows [bi + w*16, +16); A-frag per 32-col chunk
  bf16x8 aqr[8];
#pragma unroll
  for (int c8 = 0; c8 < 8; ++c8)
    aqr[c8] = *(const bf16x8*)(Qt + (long)(bi + w * 16 + l15) * 256 + c8 * 32 + quad * 8);

  f32x4 accO[4][4] = {};
  const int srow = lane >> 2, skc = (lane & 3) * 8;
  const int q0 = qq * 1024;

  for (int qt = 0; qt < 8; ++qt) {
    const int qc0 = q0 + qt * 128;
    // stage K chunk 0 into buf 0
#pragma unroll
    for (int jj = 0; jj < 2; ++jj) {
      int rbase = w * 32 + jj * 16;
      stage16(Kt + (long)(qc0 + rbase + srow) * 256 + skc, Kst[0] + rbase * 32);
    }
    __syncthreads();
    // --- S phase: dbuf K, 1 barrier per chunk ---
    f32x4 accS[8] = {};
#pragma unroll
    for (int cs = 0; cs < 8; ++cs) {
      if (cs < 7) {
#pragma unroll
        for (int jj = 0; jj < 2; ++jj) {
          int rbase = w * 32 + jj * 16;
          stage16(Kt + (long)(qc0 + rbase + srow) * 256 + (cs + 1) * 32 + skc,
                  Kst[(cs + 1) & 1] + rbase * 32);
        }
      }
      const __bf16* kb = Kst[cs & 1];
#pragma unroll
      for (int nt = 0; nt < 8; ++nt) {
        bf16x8 bk = *(const bf16x8*)(kb + (nt * 16 + l15) * 32 + quad * 8);
        accS[nt] = __builtin_amdgcn_mfma_f32_16x16x32_bf16(aqr[cs], bk, accS[nt], 0, 0, 0);
      }
      __syncthreads();   // buf reuse + next-stage visibility
    }
    // P = exp(S - m_q)*linv_q -> Pl (wave w writes its own 16 i-rows)
#pragma unroll
    for (int nt = 0; nt < 8; ++nt) {
      int q = nt * 16 + l15;
      float mq = msp[qc0 + q], lq = lsp[qc0 + q];
#pragma unroll
      for (int r = 0; r < 4; ++r) {
        int i = w * 16 + quad * 4 + r;
        Pl[i * 132 + q] = (__bf16)(exp2_fast((accS[nt][r] - mq) * LOG2E) * lq);
      }
    }
    __syncthreads();
    // --- V phase: direct-reg V, no barriers ---
#pragma unroll
    for (int qs0 = 0; qs0 < 128; qs0 += 32) {
      bf16x8 ap[4], bv[4];
#pragma unroll
      for (int mt = 0; mt < 4; ++mt)
        ap[mt] = *(const bf16x8*)(Pl + (mt * 16 + l15) * 132 + qs0 + quad * 8);
#pragma unroll
      for (int nt = 0; nt < 4; ++nt)
        bv[nt] = *(const bf16x8*)(Vv + (long)(w * 64 + nt * 16 + l15) * 4096 + qc0 + qs0 + quad * 8);
#pragma unroll
      for (int mt = 0; mt < 4; ++mt)
#pragma unroll
        for (int nt = 0; nt < 4; ++nt)
          accO[mt][nt] = __builtin_amdgcn_mfma_f32_16x16x32_bf16(ap[mt], bv[nt], accO[mt][nt], 0, 0, 0);
    }
  }
  // natural-layout fp32 partial store (coalesced 64B segments)
#pragma unroll
  for (int mt = 0; mt < 4; ++mt)
#pragma unroll
    for (int nt = 0; nt < 4; ++nt)
#pragma unroll
      for (int r = 0; r < 4; ++r) {
        int i = mt * 16 + quad * 4 + r;
        int j = w * 64 + nt * 16 + l15;
        go[(long)(bi + i) * 256 + j] = accO[mt][nt][r];
      }
}

// ---------------------------------------------------------------------------
// Sum the four q-quarter partials and write GTS in raw-reshape layout via LDS
// transpose. grid (jg 4, v 16, zbr 4), 256 threads.
__global__ __launch_bounds__(256)
void gsum_reshape(const float* __restrict__ ga, __bf16* __restrict__ gt) {
  __shared__ __bf16 lds[64 * 260];
  const int t = threadIdx.x, lane = t & 63, w = t >> 6;
  const int zbr = blockIdx.z;
  const int v   = blockIdx.y;
  const int jg  = blockIdx.x;
  const float* g0 = ga + (long)zbr * 1048576;
  for (int ci0 = 0; ci0 < 256; ci0 += 4) {
    int ci = ci0 + w;
    long src = (long)(ci * 16 + v) * 256 + jg * 64 + lane;
    float s = g0[src] + g0[src + 4194304] + g0[src + 8388608] + g0[src + 12582912];
    lds[lane * 260 + ci] = (__bf16)s;
  }
  __syncthreads();
  __bf16* out = gt + (long)zbr * 1048576 + ((long)v * 256 + jg * 64) * 256;
#pragma unroll
  for (int pp = 0; pp < 8; ++pp) {
    int idx = pp * 256 + t;
    int row = idx >> 5, c8 = (idx & 31) * 8;
    *(bf16x8*)(out + (long)row * 256 + c8) = *(const bf16x8*)(lds + row * 260 + c8);
  }
}

// ---------------------------------------------------------------------------
// Weight fold: WT = [Wfu_l*Wgs | Wfu_v*Wgs | Wfu_l | Wfu_v] (bf16 [256][1024]),
// biasT[co] = bfu[co] + sum_c (Wfu[co][c]+Wfu[co][c+256]) * bgs[c].
__global__ __launch_bounds__(256)
void wcomb(const float* __restrict__ Wgs, const float* __restrict__ bgs,
           const float* __restrict__ Wfu, const float* __restrict__ bfu,
           __bf16* __restrict__ WT, float* __restrict__ biasT)
{
  const int co = blockIdx.x, t = threadIdx.x;
  const float* wrow = Wfu + (long)co * 512;
  float accs = 0.f, accc = 0.f;
  for (int c = 0; c < 256; ++c) {
    float gv = Wgs[(long)c * 256 + t];
    accs = fmaf(wrow[c], gv, accs);
    accc = fmaf(wrow[c + 256], gv, accc);
  }
  __bf16* o = WT + (long)co * 1024;
  o[t]       = (__bf16)accs;
  o[256 + t] = (__bf16)accc;
  o[512 + t] = (__bf16)wrow[t];
  o[768 + t] = (__bf16)wrow[256 + t];
  __shared__ float red[256];
  red[t] = (wrow[t] + wrow[t + 256]) * bgs[t];
  __syncthreads();
  for (int s = 128; s > 0; s >>= 1) {
    if (t < s) red[t] += red[t + s];
    __syncthreads();
  }
  if (t == 0) biasT[co] = bfu[co] + red[0];
}

// ---------------------------------------------------------------------------
// Tail GEMM: out[z][co][p] = sum_k WT[co][k] * Bcat[z][p][k] + biasT[co],
// Bcat k-groups: 0 GTS_s, 1 GTS_c, 2 Xt(Fl), 3 Xt(Fv). grid (32, 2, 2).
__global__ __launch_bounds__(256)
void tail_gemm(const __bf16* __restrict__ WT, const __bf16* __restrict__ GTS,
               const __bf16* __restrict__ Xt, const float* __restrict__ biasT,
               float* __restrict__ out)
{
  __shared__ __align__(16) __bf16 smem[8192];
  __bf16* As = smem;
  __bf16* Bs = smem + 4096;

  const int tid  = threadIdx.x;
  const int lane = tid & 63;
  const int w    = tid >> 6;
  const int wm   = (w >> 1) * 64;
  const int wn   = (w & 1) * 64;
  const int z    = blockIdx.z;
  const int bm   = blockIdx.y * 128;
  const int bn   = blockIdx.x * 128;

  const __bf16* Bsel[4] = {
    GTS + (long)z * 1048576, GTS + (long)(2 + z) * 1048576,
    Xt  + (long)z * 1048576, Xt  + (long)(2 + z) * 1048576
  };

  f32x4 acc[4][4] = {};
  const int srow = lane >> 2;
  const int skc  = (lane & 3) * 8;

  for (int k0 = 0; k0 < 1024; k0 += 32) {
    const __bf16* Bb = Bsel[k0 >> 8];
    const int kk = k0 & 255;
#pragma unroll
    for (int j = 0; j < 2; ++j) {
      int rbase = w * 32 + j * 16;
      stage16(WT + (long)(bm + rbase + srow) * 1024 + k0 + skc, As + rbase * 32);
    }
#pragma unroll
    for (int j = 0; j < 2; ++j) {
      int rbase = w * 32 + j * 16;
      stage16(Bb + (long)(bn + rbase + srow) * 256 + kk + skc, Bs + rbase * 32);
    }
    __syncthreads();
    bf16x8 af[4], bfr[4];
#pragma unroll
    for (int t = 0; t < 4; ++t)
      af[t] = *(const bf16x8*)(As + (wm + t * 16 + (lane & 15)) * 32 + (lane >> 4) * 8);
#pragma unroll
    for (int t = 0; t < 4; ++t)
      bfr[t] = *(const bf16x8*)(Bs + (wn + t * 16 + (lane & 15)) * 32 + (lane >> 4) * 8);
#pragma unroll
    for (int mt = 0; mt < 4; ++mt)
#pragma unroll
      for (int nt = 0; nt < 4; ++nt)
        acc[mt][nt] = __builtin_amdgcn_mfma_f32_16x16x32_bf16(af[mt], bfr[nt], acc[mt][nt], 0, 0, 0);
    __syncthreads();
  }

#pragma unroll
  for (int mt = 0; mt < 4; ++mt)
#pragma unroll
    for (int nt = 0; nt < 4; ++nt)
#pragma unroll
      for (int r = 0; r < 4; ++r) {
        int m = bm + wm + mt * 16 + (lane >> 4) * 4 + r;
        int n = bn + wn + nt * 16 + (lane & 15);
        out[((long)z * 256 + m) * HWSZ + n] = acc[mt][nt][r] + biasT[m];
      }
}

// ---------------------------------------------------------------------------
// Fl/Fv [b][256][4096] fp32 -> Xt [img][4096][256] bf16 (Fl b0, Fl b1, Fv b0, Fv b1)
__global__ void transpose_cvt(const float* __restrict__ F0, const float* __restrict__ F1,
                              __bf16* __restrict__ Xt) {
  __shared__ float tile[32][33];
  int img = blockIdx.z;
  const float* src = (img < 2 ? F0 : F1) + (long)(img & 1) * (CCH * HWSZ);
  __bf16* dst = Xt + (long)img * (HWSZ * CCH);
  int p0 = blockIdx.x * 32, c0 = blockIdx.y * 32;
  int tx = threadIdx.x, ty = threadIdx.y;
#pragma unroll
  for (int j = 0; j < 32; j += 8)
    tile[ty + j][tx] = src[(long)(c0 + ty + j) * HWSZ + p0 + tx];
  __syncthreads();
#pragma unroll
  for (int j = 0; j < 32; j += 8)
    dst[(long)(p0 + ty + j) * CCH + c0 + tx] = (__bf16)tile[tx][ty + j];
}

// Xt -> im2col Cc [img][4096][2304], k = t*256+ci, zero-padded borders
__global__ void im2col_k(const __bf16* __restrict__ Xt, __bf16* __restrict__ Cc) {
  int img = blockIdx.y;
  int e = blockIdx.x * 256 + threadIdx.x;
  int p = e / 288;
  int c8 = e - p * 288;
  int t = c8 >> 5;
  int ci0 = (c8 & 31) * 8;
  int dy = t / 3 - 1, dx = t - (t / 3) * 3 - 1;
  int y = p >> 6, x = p & 63;
  int yy = y + dy, xx = x + dx;
  const __bf16* src = Xt + (long)img * (HWSZ * CCH);
  __bf16* dst = Cc + (long)img * 9437184 + (long)p * 2304 + t * 256 + ci0;
  uint4 v = make_uint4(0u, 0u, 0u, 0u);
  if ((unsigned)yy < 64u && (unsigned)xx < 64u)
    v = *(const uint4*)(src + (long)(yy * 64 + xx) * CCH + ci0);
  *(uint4*)dst = v;
}

// W[co][ci][3][3] fp32 -> A[co][t*256+ci] bf16, stacked AL (Wqs,Wks,Wvs,Wqc), AV (Wkc,Wvc)
struct W6 { const float* w[6]; };
__global__ void repack_w3(W6 wp, __bf16* __restrict__ AL, __bf16* __restrict__ AV) {
  int zi = blockIdx.y;
  int e = blockIdx.x * 256 + threadIdx.x;
  int co = e / 2304;
  int rem = e - co * 2304;
  int t = rem >> 8, ci = rem & 255;
  float v = wp.w[zi][(long)co * 2304 + ci * 9 + t];
  __bf16* dst = (zi < 4) ? (AL + (long)zi * 256 * 2304) : (AV + (long)(zi - 4) * 256 * 2304);
  dst[(long)co * 2304 + rem] = (__bf16)v;
}

// ---------------------------------------------------------------------------
extern "C" void kernel_launch(void* const* d_in, const int* in_sizes, int n_in,
                              void* d_out, int out_size, void* d_ws, size_t ws_size,
                              hipStream_t stream) {
  const float* Fl  = (const float*)d_in[0];
  const float* Fv  = (const float*)d_in[1];
  const float* Wqs = (const float*)d_in[2];  const float* bqs = (const float*)d_in[3];
  const float* Wks = (const float*)d_in[4];  const float* bks = (const float*)d_in[5];
  const float* Wvs = (const float*)d_in[6];  const float* bvs = (const float*)d_in[7];
  const float* Wqc = (const float*)d_in[8];  const float* bqc = (const float*)d_in[9];
  const float* Wkc = (const float*)d_in[10]; const float* bkc = (const float*)d_in[11];
  const float* Wvc = (const float*)d_in[12]; const float* bvc = (const float*)d_in[13];
  const float* Wgs = (const float*)d_in[14]; const float* bgs = (const float*)d_in[15];
  const float* Wfu = (const float*)d_in[16]; const float* bfu = (const float*)d_in[17];

  char* ws = (char*)d_ws;
  size_t off = 0;
  auto take = [&](size_t bytes) -> void* {
    void* p = ws + off; off = (off + bytes + 255) & ~(size_t)255; return p;
  };
  __bf16* QST  = (__bf16*)take(4194304);   // Qs^T  [b][4096][256]
  __bf16* KST  = (__bf16*)take(4194304);
  __bf16* QCT  = (__bf16*)take(4194304);
  __bf16* KCT  = (__bf16*)take(4194304);
  __bf16* VS   = (__bf16*)take(4194304);   // Vs    [b][256][4096]
  __bf16* VC   = (__bf16*)take(4194304);
  __bf16* GTS  = (__bf16*)take(8388608);   // G (reshape layout) [br*2+z][4096][256]
  __bf16* AL   = (__bf16*)take(4718592);   // conv weights [1024][2304]
  __bf16* AV   = (__bf16*)take(2359296);   // [512][2304]
  __bf16* WT   = (__bf16*)take(524288);    // folded tail weights [256][1024]
  float*  BT   = (float*)take(1024);       // folded tail bias [256]
  float*  MST  = (float*)take(65536);      // [br*2+z][4096]
  float*  LST  = (float*)take(65536);
  float*  PM   = (float*)take(131072);     // partial stats [ih][zbr][4096]
  float*  PL   = (float*)take(131072);
  __bf16* Xt   = (__bf16*)take(8388608);   // [img][4096][256] — alive through tail
  size_t ovl = off;                        // overlay: Cc (conv) / GACC (attn)
  __bf16* Cc = (__bf16*)take(75497472);
  size_t needConv = off;
  float* GACC = (float*)(ws + ovl);        // [4 qq][4 zbr][4096*256] fp32 = 64 MB
  size_t needAttn = ovl + 67108864;
  size_t need = needConv > needAttn ? needConv : needAttn;
  if (ws_size < need) return;

  transpose_cvt<<<dim3(128, 8, 4), dim3(32, 8), 0, stream>>>(Fl, Fv, Xt);
  im2col_k<<<dim3(4608, 4), 256, 0, stream>>>(Xt, Cc);
  W6 wp; wp.w[0]=Wqs; wp.w[1]=Wks; wp.w[2]=Wvs; wp.w[3]=Wqc; wp.w[4]=Wkc; wp.w[5]=Wvc;
  repack_w3<<<dim3(2304, 6), 256, 0, stream>>>(wp, AL, AV);
  wcomb<<<dim3(256), 256, 0, stream>>>(Wgs, bgs, Wfu, bfu, WT, BT);

  gemm_conv<<<dim3(32, 12, 2), 256, 0, stream>>>(
      AL, AV, Cc, QST, KST, VS, QCT, KCT, VC,
      bqs, bks, bvs, bqc, bkc, bvc);

  qk_stats<<<dim3(512), 256, 0, stream>>>(QST, QCT, KST, KCT, PM, PL);
  stats_combine2<<<dim3(16, 4), 256, 0, stream>>>(PM, PL, MST, LST);

  fused_pv<<<dim3(1024), 256, 0, stream>>>(
      QST, QCT, KST, KCT, VS, VC, MST, LST, GACC);

  gsum_reshape<<<dim3(4, 16, 4), 256, 0, stream>>>(GACC, GTS);

  tail_gemm<<<dim3(32, 2, 2), 256, 0, stream>>>(WT, GTS, Xt, BT, (float*)d_out);
}

// Round 10
// 443.571 us; speedup vs baseline: 1.1877x; 1.0285x over previous
//
#include <hip/hip_runtime.h>

typedef __bf16 bf16x4 __attribute__((ext_vector_type(4)));
typedef __bf16 bf16x8 __attribute__((ext_vector_type(8)));
typedef float  f32x4  __attribute__((ext_vector_type(4)));

#define HWSZ 4096
#define CCH  256
#define LOG2E 1.44269504088896340736f

__device__ __forceinline__ float exp2_fast(float x) {
#if __has_builtin(__builtin_amdgcn_exp2f)
  return __builtin_amdgcn_exp2f(x);
#else
  return exp2f(x);
#endif
}

// stage 16B per lane into LDS; lane's data lands at lds_base + lane*16B
__device__ __forceinline__ void stage16(const __bf16* g, __bf16* ldsBase) {
#if __has_builtin(__builtin_amdgcn_global_load_lds)
  __builtin_amdgcn_global_load_lds(
      (const __attribute__((address_space(1))) void*)g,
      (__attribute__((address_space(3))) void*)ldsBase, 16, 0, 0);
#else
  int lane = threadIdx.x & 63;
  *(bf16x8*)(ldsBase + lane * 8) = *(const bf16x8*)g;
#endif
}

// XOR swizzle for 32-elem-row LDS tiles: phys 16B-chunk = logical ^ ((row>>1)&3).
// Staging lane (srow=lane>>2, cg=lane&3) fetches logical chunk cg^((srow>>1)&3):
//   global column offset = SWZ_STAGE(lane)
// Fragment read of logical chunk `quad` at row l15: phys offset = SWZ_READ(quad, lane)
// Result: ds_read_b128 bank groups 8-distinct x 2 lanes = 2-way (free) vs 8-way.
#define SWZ_STAGE(lane) ((((lane) & 3) ^ (((lane) >> 3) & 3)) * 8)
#define SWZ_READ(quad, lane) ((((quad) ^ (((lane) >> 1) & 3))) * 8)

// ---------------------------------------------------------------------------
// Merged conv3x3 GEMM (128x128x32 MFMA): by<8 -> A=AL (Qs,Ks,Vs,Qc from Fl),
// else A=AV (Kc,Vc from Fv). B = im2col Cc [img][4096][2304]. Swizzled LDS.
// ---------------------------------------------------------------------------
__global__ __launch_bounds__(256)
void gemm_conv(const __bf16* __restrict__ AL, const __bf16* __restrict__ AV,
               const __bf16* __restrict__ Cc,
               __bf16* __restrict__ qst, __bf16* __restrict__ kst,
               __bf16* __restrict__ vs,  __bf16* __restrict__ qct,
               __bf16* __restrict__ kct, __bf16* __restrict__ vc,
               const float* __restrict__ bqs, const float* __restrict__ bks,
               const float* __restrict__ bvs, const float* __restrict__ bqc,
               const float* __restrict__ bkc, const float* __restrict__ bvc)
{
  __shared__ __align__(16) __bf16 smem[8192];
  __bf16* As = smem;
  __bf16* Bs = smem + 4096;

  const int tid  = threadIdx.x;
  const int lane = tid & 63;
  const int w    = tid >> 6;
  const int wm   = (w >> 1) * 64;
  const int wn   = (w & 1) * 64;
  const int z    = blockIdx.z;
  const int by   = blockIdx.y;
  const int bn   = blockIdx.x * 128;
  const int K    = 2304;

  const bool isL = (by < 8);
  const int bm = (isL ? by : by - 8) * 128;
  const __bf16* Ab = isL ? AL : AV;
  const __bf16* Bb = Cc + (long)((isL ? 0 : 2) + z) * 9437184;

  f32x4 acc[4][4] = {};
  const int srow = lane >> 2;
  const int skc  = SWZ_STAGE(lane);
  const int quad = lane >> 4, l15 = lane & 15;
  const int rdo  = SWZ_READ(quad, lane);

  for (int k0 = 0; k0 < K; k0 += 32) {
#pragma unroll
    for (int j = 0; j < 2; ++j) {
      int rbase = w * 32 + j * 16;
      stage16(Ab + (long)(bm + rbase + srow) * K + k0 + skc, As + rbase * 32);
    }
#pragma unroll
    for (int j = 0; j < 2; ++j) {
      int rbase = w * 32 + j * 16;
      stage16(Bb + (long)(bn + rbase + srow) * K + k0 + skc, Bs + rbase * 32);
    }
    __syncthreads();
    bf16x8 af[4], bfr[4];
#pragma unroll
    for (int t = 0; t < 4; ++t)
      af[t] = *(const bf16x8*)(As + (wm + t * 16 + l15) * 32 + rdo);
#pragma unroll
    for (int t = 0; t < 4; ++t)
      bfr[t] = *(const bf16x8*)(Bs + (wn + t * 16 + l15) * 32 + rdo);
#pragma unroll
    for (int mt = 0; mt < 4; ++mt)
#pragma unroll
      for (int nt = 0; nt < 4; ++nt)
        acc[mt][nt] = __builtin_amdgcn_mfma_f32_16x16x32_bf16(af[mt], bfr[nt], acc[mt][nt], 0, 0, 0);
    __syncthreads();
  }

#pragma unroll
  for (int mt = 0; mt < 4; ++mt) {
#pragma unroll
    for (int nt = 0; nt < 4; ++nt) {
#pragma unroll
      for (int r = 0; r < 4; ++r) {
        int m = bm + wm + mt * 16 + quad * 4 + r;
        int n = bn + wn + nt * 16 + l15;
        int g = m >> 8, mm = m & 255;
        const float* bias; __bf16* op; bool vlay;
        if (isL) {
          bias = (g == 0) ? bqs : (g == 1) ? bks : (g == 2) ? bvs : bqc;
          op   = (g == 0) ? qst : (g == 1) ? kst : (g == 2) ? vs  : qct;
          vlay = (g == 2);
        } else {
          bias = g ? bvc : bkc;
          op   = g ? vc  : kct;
          vlay = (g == 1);
        }
        float vv = acc[mt][nt][r] + bias[mm];
        if (vlay) op[(long)z * 1048576 + (long)mm * HWSZ + n] = (__bf16)vv;   // V: [c,p]
        else      op[(long)z * 1048576 + (long)n * CCH + mm] = (__bf16)vv;    // Q/K: [p,c]
      }
    }
  }
}

// ---------------------------------------------------------------------------
// qk_stats: partial column-softmax stats over HALF the i-range.
// 1-D grid 512: lid -> (g: z,br | ih | qb). Kres stride 260 (conflict-free).
// ---------------------------------------------------------------------------
__global__ __launch_bounds__(256)
void qk_stats(const __bf16* __restrict__ qs, const __bf16* __restrict__ qc,
              const __bf16* __restrict__ ks, const __bf16* __restrict__ kc,
              float* __restrict__ pm, float* __restrict__ pl)
{
  __shared__ __align__(16) __bf16 Kres[64 * 260];
  __shared__ float wm_[4][64], wl_[4][64];

  const int tid = threadIdx.x, lane = tid & 63, w = tid >> 6;
  const int quad = lane >> 4, l15 = lane & 15;
  const int lid = blockIdx.x;
  const int g = lid & 3;
  const int z = g & 1, br = g >> 1;
  const int ih = (lid >> 2) & 1;
  const int qb = (lid >> 3) * 64;
  const __bf16* Qt = (br ? qc : qs) + (long)z * 1048576;
  const __bf16* Kt = (br ? kc : ks) + (long)z * 1048576;

  for (int idx = tid; idx < 2048; idx += 256) {
    int r = idx >> 5, c8 = (idx & 31) * 8;
    *(bf16x8*)(Kres + r * 260 + c8) = *(const bf16x8*)(Kt + (long)(qb + r) * 256 + c8);
  }
  __syncthreads();

  float rm[4], rl[4];
#pragma unroll
  for (int nt = 0; nt < 4; ++nt) { rm[nt] = -3.0e38f; rl[nt] = 0.f; }

  for (int it = 0; it < 8; ++it) {
    const int i0 = ih * 2048 + it * 256 + w * 64;
    f32x4 accS[4][4] = {};
#pragma unroll
    for (int cs = 0; cs < 256; cs += 32) {
      bf16x8 a[4], b[4];
#pragma unroll
      for (int mt = 0; mt < 4; ++mt)
        a[mt] = *(const bf16x8*)(Qt + (long)(i0 + mt * 16 + l15) * 256 + cs + quad * 8);
#pragma unroll
      for (int nt = 0; nt < 4; ++nt)
        b[nt] = *(const bf16x8*)(Kres + (nt * 16 + l15) * 260 + cs + quad * 8);
#pragma unroll
      for (int mt = 0; mt < 4; ++mt)
#pragma unroll
        for (int nt = 0; nt < 4; ++nt)
          accS[mt][nt] = __builtin_amdgcn_mfma_f32_16x16x32_bf16(a[mt], b[nt], accS[mt][nt], 0, 0, 0);
    }
#pragma unroll
    for (int nt = 0; nt < 4; ++nt) {
      float mx = -3.0e38f;
#pragma unroll
      for (int mt = 0; mt < 4; ++mt)
#pragma unroll
        for (int r = 0; r < 4; ++r) mx = fmaxf(mx, accS[mt][nt][r]);
      float sl = 0.f;
#pragma unroll
      for (int mt = 0; mt < 4; ++mt)
#pragma unroll
        for (int r = 0; r < 4; ++r) sl += exp2_fast((accS[mt][nt][r] - mx) * LOG2E);
#pragma unroll
      for (int d = 16; d <= 32; d <<= 1) {
        float om = __shfl_xor(mx, d, 64);
        float ol = __shfl_xor(sl, d, 64);
        float nm = fmaxf(mx, om);
        sl = sl * exp2_fast((mx - nm) * LOG2E) + ol * exp2_fast((om - nm) * LOG2E);
        mx = nm;
      }
      float nm = fmaxf(rm[nt], mx);
      rl[nt] = rl[nt] * exp2_fast((rm[nt] - nm) * LOG2E) + sl * exp2_fast((mx - nm) * LOG2E);
      rm[nt] = nm;
    }
  }
  if (lane < 16) {
#pragma unroll
    for (int nt = 0; nt < 4; ++nt) { wm_[w][nt * 16 + lane] = rm[nt]; wl_[w][nt * 16 + lane] = rl[nt]; }
  }
  __syncthreads();
  if (tid < 64) {
    float m = -3.0e38f;
#pragma unroll
    for (int ww = 0; ww < 4; ++ww) m = fmaxf(m, wm_[ww][tid]);
    float l = 0.f;
#pragma unroll
    for (int ww = 0; ww < 4; ++ww)
      l += wl_[ww][tid] * exp2_fast((wm_[ww][tid] - m) * LOG2E);
    long o = ((long)ih * 4 + br * 2 + z) * 4096 + qb + tid;
    pm[o] = m;
    pl[o] = l;
  }
}

// combine the two i-half partials -> final m, 1/l. grid (16, 4 zbr), 256 thr.
__global__ void stats_combine2(const float* __restrict__ pm, const float* __restrict__ pl,
                               float* __restrict__ mst, float* __restrict__ lst) {
  int q = blockIdx.x * 256 + threadIdx.x;
  int zbr = blockIdx.y;
  float m0 = pm[(long)zbr * 4096 + q],        l0 = pl[(long)zbr * 4096 + q];
  float m1 = pm[(long)(4 + zbr) * 4096 + q],  l1 = pl[(long)(4 + zbr) * 4096 + q];
  float m = fmaxf(m0, m1);
  float l = l0 * exp2_fast((m0 - m) * LOG2E) + l1 * exp2_fast((m1 - m) * LOG2E);
  mst[(long)zbr * 4096 + q] = m;
  lst[(long)zbr * 4096 + q] = 1.0f / l;
}

// ---------------------------------------------------------------------------
// Fused recompute-S PV (round-7 structure + swizzled Kst):
// Block: i-tile 64 (Q LDS-resident, stride 260 conflict-free), one (zbr),
// one q-half. S-phase: staged K (global_load_lds, XOR-swizzled -> 2-way);
// per-thread register stats; V direct global->reg. Grid 512 XCD-swizzled.
// ---------------------------------------------------------------------------
__global__ __launch_bounds__(256)
void fused_pv(const __bf16* __restrict__ qs, const __bf16* __restrict__ qc,
              const __bf16* __restrict__ ks, const __bf16* __restrict__ kc,
              const __bf16* __restrict__ vs, const __bf16* __restrict__ vc,
              const float* __restrict__ mst, const float* __restrict__ lst,
              float* __restrict__ gacc)
{
  __shared__ __align__(16) __bf16 Qres[64 * 260];   // 33.3 KB (conflict-free)
  __shared__ __align__(16) __bf16 Pl[64 * 132];     // 16.9 KB (conflict-free)
  __shared__ __align__(16) __bf16 Kst[128 * 32];    //  8.0 KB (swizzled)

  const int tid = threadIdx.x, lane = tid & 63, w = tid >> 6;
  const int quad = lane >> 4, l15 = lane & 15;
  const int lid = blockIdx.x;
  const int g   = lid & 7;
  const int zbr = g >> 1;
  const int qh  = g & 1;
  const int bi  = (lid >> 3) * 64;
  const int br = zbr >> 1, z = zbr & 1;
  const __bf16* Qt = (br ? qc : qs) + (long)z * 1048576;
  const __bf16* Kt = (br ? kc : ks) + (long)z * 1048576;
  const __bf16* Vv = (br ? vc : vs) + (long)z * 1048576;
  const float* msp = mst + (long)zbr * 4096;
  const float* lsp = lst + (long)zbr * 4096;
  float* go = gacc + ((long)qh * 4 + zbr) * 1048576;

  for (int idx = tid; idx < 2048; idx += 256) {
    int r = idx >> 5, c8 = (idx & 31) * 8;
    *(bf16x8*)(Qres + r * 260 + c8) = *(const bf16x8*)(Qt + (long)(bi + r) * 256 + c8);
  }

  f32x4 accO[4][4] = {};
  const int srow = lane >> 2;
  const int skc  = SWZ_STAGE(lane);
  const int rdo  = SWZ_READ(quad, lane);
  const int q0 = qh * 2048;

  for (int qc0 = q0; qc0 < q0 + 2048; qc0 += 128) {
    // --- S phase: staged swizzled K ---
    f32x4 accS[4][2] = {};
#pragma unroll
    for (int cs = 0; cs < 256; cs += 32) {
#pragma unroll
      for (int jj = 0; jj < 2; ++jj) {
        int rbase = w * 32 + jj * 16;
        stage16(Kt + (long)(qc0 + rbase + srow) * 256 + cs + skc, Kst + rbase * 32);
      }
      __syncthreads();
      bf16x8 aq[4], bk[2];
#pragma unroll
      for (int mt = 0; mt < 4; ++mt)
        aq[mt] = *(const bf16x8*)(Qres + (mt * 16 + l15) * 260 + cs + quad * 8);
#pragma unroll
      for (int nt = 0; nt < 2; ++nt)
        bk[nt] = *(const bf16x8*)(Kst + (w * 32 + nt * 16 + l15) * 32 + rdo);
#pragma unroll
      for (int mt = 0; mt < 4; ++mt)
#pragma unroll
        for (int nt = 0; nt < 2; ++nt)
          accS[mt][nt] = __builtin_amdgcn_mfma_f32_16x16x32_bf16(aq[mt], bk[nt], accS[mt][nt], 0, 0, 0);
      __syncthreads();
    }
    // P = exp(S - m_q)*linv_q -> Pl (stats direct from global, per-thread regs)
#pragma unroll
    for (int nt = 0; nt < 2; ++nt) {
      int q = w * 32 + nt * 16 + l15;
      float mq = msp[qc0 + q], lq = lsp[qc0 + q];
#pragma unroll
      for (int mt = 0; mt < 4; ++mt)
#pragma unroll
        for (int r = 0; r < 4; ++r) {
          int i = mt * 16 + quad * 4 + r;
          Pl[i * 132 + q] = (__bf16)(exp2_fast((accS[mt][nt][r] - mq) * LOG2E) * lq);
        }
    }
    __syncthreads();
    // --- V phase: direct-reg V (independent, hoistable), no barriers ---
#pragma unroll
    for (int qs0 = 0; qs0 < 128; qs0 += 32) {
      bf16x8 ap[4], bv[4];
#pragma unroll
      for (int mt = 0; mt < 4; ++mt)
        ap[mt] = *(const bf16x8*)(Pl + (mt * 16 + l15) * 132 + qs0 + quad * 8);
#pragma unroll
      for (int nt = 0; nt < 4; ++nt)
        bv[nt] = *(const bf16x8*)(Vv + (long)(w * 64 + nt * 16 + l15) * 4096 + qc0 + qs0 + quad * 8);
#pragma unroll
      for (int mt = 0; mt < 4; ++mt)
#pragma unroll
        for (int nt = 0; nt < 4; ++nt)
          accO[mt][nt] = __builtin_amdgcn_mfma_f32_16x16x32_bf16(ap[mt], bv[nt], accO[mt][nt], 0, 0, 0);
    }
  }
  // natural-layout fp32 partial store (coalesced 64B segments)
#pragma unroll
  for (int mt = 0; mt < 4; ++mt)
#pragma unroll
    for (int nt = 0; nt < 4; ++nt)
#pragma unroll
      for (int r = 0; r < 4; ++r) {
        int i = mt * 16 + quad * 4 + r;
        int j = w * 64 + nt * 16 + l15;
        go[(long)(bi + i) * 256 + j] = accO[mt][nt][r];
      }
}

// ---------------------------------------------------------------------------
// Sum the two q-half partials and write GTS in raw-reshape layout via LDS
// transpose. grid (jg 4, v 16, zbr 4), 256 threads.
__global__ __launch_bounds__(256)
void gsum_reshape(const float* __restrict__ ga, __bf16* __restrict__ gt) {
  __shared__ __bf16 lds[64 * 260];
  const int t = threadIdx.x, lane = t & 63, w = t >> 6;
  const int zbr = blockIdx.z;
  const int v   = blockIdx.y;
  const int jg  = blockIdx.x;
  const float* g0 = ga + (long)zbr * 1048576;
  const float* g1 = g0 + 4194304;
  for (int ci0 = 0; ci0 < 256; ci0 += 4) {
    int ci = ci0 + w;
    long src = (long)(ci * 16 + v) * 256 + jg * 64 + lane;
    lds[lane * 260 + ci] = (__bf16)(g0[src] + g1[src]);
  }
  __syncthreads();
  __bf16* out = gt + (long)zbr * 1048576 + ((long)v * 256 + jg * 64) * 256;
#pragma unroll
  for (int pp = 0; pp < 8; ++pp) {
    int idx = pp * 256 + t;
    int row = idx >> 5, c8 = (idx & 31) * 8;
    *(bf16x8*)(out + (long)row * 256 + c8) = *(const bf16x8*)(lds + row * 260 + c8);
  }
}

// ---------------------------------------------------------------------------
// Weight fold: WT = [Wfu_l*Wgs | Wfu_v*Wgs | Wfu_l | Wfu_v] (bf16 [256][1024]),
// biasT[co] = bfu[co] + sum_c (Wfu[co][c]+Wfu[co][c+256]) * bgs[c].
__global__ __launch_bounds__(256)
void wcomb(const float* __restrict__ Wgs, const float* __restrict__ bgs,
           const float* __restrict__ Wfu, const float* __restrict__ bfu,
           __bf16* __restrict__ WT, float* __restrict__ biasT)
{
  const int co = blockIdx.x, t = threadIdx.x;
  const float* wrow = Wfu + (long)co * 512;
  float accs = 0.f, accc = 0.f;
  for (int c = 0; c < 256; ++c) {
    float gv = Wgs[(long)c * 256 + t];
    accs = fmaf(wrow[c], gv, accs);
    accc = fmaf(wrow[c + 256], gv, accc);
  }
  __bf16* o = WT + (long)co * 1024;
  o[t]       = (__bf16)accs;
  o[256 + t] = (__bf16)accc;
  o[512 + t] = (__bf16)wrow[t];
  o[768 + t] = (__bf16)wrow[256 + t];
  __shared__ float red[256];
  red[t] = (wrow[t] + wrow[t + 256]) * bgs[t];
  __syncthreads();
  for (int s = 128; s > 0; s >>= 1) {
    if (t < s) red[t] += red[t + s];
    __syncthreads();
  }
  if (t == 0) biasT[co] = bfu[co] + red[0];
}

// ---------------------------------------------------------------------------
// Tail GEMM: out[z][co][p] = sum_k WT[co][k] * Bcat[z][p][k] + biasT[co],
// Bcat k-groups: 0 GTS_s, 1 GTS_c, 2 Xt(Fl), 3 Xt(Fv). Swizzled LDS.
__global__ __launch_bounds__(256)
void tail_gemm(const __bf16* __restrict__ WT, const __bf16* __restrict__ GTS,
               const __bf16* __restrict__ Xt, const float* __restrict__ biasT,
               float* __restrict__ out)
{
  __shared__ __align__(16) __bf16 smem[8192];
  __bf16* As = smem;
  __bf16* Bs = smem + 4096;

  const int tid  = threadIdx.x;
  const int lane = tid & 63;
  const int w    = tid >> 6;
  const int wm   = (w >> 1) * 64;
  const int wn   = (w & 1) * 64;
  const int z    = blockIdx.z;
  const int bm   = blockIdx.y * 128;
  const int bn   = blockIdx.x * 128;

  const __bf16* Bsel[4] = {
    GTS + (long)z * 1048576, GTS + (long)(2 + z) * 1048576,
    Xt  + (long)z * 1048576, Xt  + (long)(2 + z) * 1048576
  };

  f32x4 acc[4][4] = {};
  const int srow = lane >> 2;
  const int skc  = SWZ_STAGE(lane);
  const int quad = lane >> 4, l15 = lane & 15;
  const int rdo  = SWZ_READ(quad, lane);

  for (int k0 = 0; k0 < 1024; k0 += 32) {
    const __bf16* Bb = Bsel[k0 >> 8];
    const int kk = k0 & 255;
#pragma unroll
    for (int j = 0; j < 2; ++j) {
      int rbase = w * 32 + j * 16;
      stage16(WT + (long)(bm + rbase + srow) * 1024 + k0 + skc, As + rbase * 32);
    }
#pragma unroll
    for (int j = 0; j < 2; ++j) {
      int rbase = w * 32 + j * 16;
      stage16(Bb + (long)(bn + rbase + srow) * 256 + kk + skc, Bs + rbase * 32);
    }
    __syncthreads();
    bf16x8 af[4], bfr[4];
#pragma unroll
    for (int t = 0; t < 4; ++t)
      af[t] = *(const bf16x8*)(As + (wm + t * 16 + l15) * 32 + rdo);
#pragma unroll
    for (int t = 0; t < 4; ++t)
      bfr[t] = *(const bf16x8*)(Bs + (wn + t * 16 + l15) * 32 + rdo);
#pragma unroll
    for (int mt = 0; mt < 4; ++mt)
#pragma unroll
      for (int nt = 0; nt < 4; ++nt)
        acc[mt][nt] = __builtin_amdgcn_mfma_f32_16x16x32_bf16(af[mt], bfr[nt], acc[mt][nt], 0, 0, 0);
    __syncthreads();
  }

#pragma unroll
  for (int mt = 0; mt < 4; ++mt)
#pragma unroll
    for (int nt = 0; nt < 4; ++nt)
#pragma unroll
      for (int r = 0; r < 4; ++r) {
        int m = bm + wm + mt * 16 + quad * 4 + r;
        int n = bn + wn + nt * 16 + l15;
        out[((long)z * 256 + m) * HWSZ + n] = acc[mt][nt][r] + biasT[m];
      }
}

// ---------------------------------------------------------------------------
// Fl/Fv [b][256][4096] fp32 -> Xt [img][4096][256] bf16 (Fl b0, Fl b1, Fv b0, Fv b1)
__global__ void transpose_cvt(const float* __restrict__ F0, const float* __restrict__ F1,
                              __bf16* __restrict__ Xt) {
  __shared__ float tile[32][33];
  int img = blockIdx.z;
  const float* src = (img < 2 ? F0 : F1) + (long)(img & 1) * (CCH * HWSZ);
  __bf16* dst = Xt + (long)img * (HWSZ * CCH);
  int p0 = blockIdx.x * 32, c0 = blockIdx.y * 32;
  int tx = threadIdx.x, ty = threadIdx.y;
#pragma unroll
  for (int j = 0; j < 32; j += 8)
    tile[ty + j][tx] = src[(long)(c0 + ty + j) * HWSZ + p0 + tx];
  __syncthreads();
#pragma unroll
  for (int j = 0; j < 32; j += 8)
    dst[(long)(p0 + ty + j) * CCH + c0 + tx] = (__bf16)tile[tx][ty + j];
}

// Xt -> im2col Cc [img][4096][2304], k = t*256+ci, zero-padded borders
__global__ void im2col_k(const __bf16* __restrict__ Xt, __bf16* __restrict__ Cc) {
  int img = blockIdx.y;
  int e = blockIdx.x * 256 + threadIdx.x;
  int p = e / 288;
  int c8 = e - p * 288;
  int t = c8 >> 5;
  int ci0 = (c8 & 31) * 8;
  int dy = t / 3 - 1, dx = t - (t / 3) * 3 - 1;
  int y = p >> 6, x = p & 63;
  int yy = y + dy, xx = x + dx;
  const __bf16* src = Xt + (long)img * (HWSZ * CCH);
  __bf16* dst = Cc + (long)img * 9437184 + (long)p * 2304 + t * 256 + ci0;
  uint4 v = make_uint4(0u, 0u, 0u, 0u);
  if ((unsigned)yy < 64u && (unsigned)xx < 64u)
    v = *(const uint4*)(src + (long)(yy * 64 + xx) * CCH + ci0);
  *(uint4*)dst = v;
}

// W[co][ci][3][3] fp32 -> A[co][t*256+ci] bf16, stacked AL (Wqs,Wks,Wvs,Wqc), AV (Wkc,Wvc)
struct W6 { const float* w[6]; };
__global__ void repack_w3(W6 wp, __bf16* __restrict__ AL, __bf16* __restrict__ AV) {
  int zi = blockIdx.y;
  int e = blockIdx.x * 256 + threadIdx.x;
  int co = e / 2304;
  int rem = e - co * 2304;
  int t = rem >> 8, ci = rem & 255;
  float v = wp.w[zi][(long)co * 2304 + ci * 9 + t];
  __bf16* dst = (zi < 4) ? (AL + (long)zi * 256 * 2304) : (AV + (long)(zi - 4) * 256 * 2304);
  dst[(long)co * 2304 + rem] = (__bf16)v;
}

// ---------------------------------------------------------------------------
extern "C" void kernel_launch(void* const* d_in, const int* in_sizes, int n_in,
                              void* d_out, int out_size, void* d_ws, size_t ws_size,
                              hipStream_t stream) {
  const float* Fl  = (const float*)d_in[0];
  const float* Fv  = (const float*)d_in[1];
  const float* Wqs = (const float*)d_in[2];  const float* bqs = (const float*)d_in[3];
  const float* Wks = (const float*)d_in[4];  const float* bks = (const float*)d_in[5];
  const float* Wvs = (const float*)d_in[6];  const float* bvs = (const float*)d_in[7];
  const float* Wqc = (const float*)d_in[8];  const float* bqc = (const float*)d_in[9];
  const float* Wkc = (const float*)d_in[10]; const float* bkc = (const float*)d_in[11];
  const float* Wvc = (const float*)d_in[12]; const float* bvc = (const float*)d_in[13];
  const float* Wgs = (const float*)d_in[14]; const float* bgs = (const float*)d_in[15];
  const float* Wfu = (const float*)d_in[16]; const float* bfu = (const float*)d_in[17];

  char* ws = (char*)d_ws;
  size_t off = 0;
  auto take = [&](size_t bytes) -> void* {
    void* p = ws + off; off = (off + bytes + 255) & ~(size_t)255; return p;
  };
  __bf16* QST  = (__bf16*)take(4194304);   // Qs^T  [b][4096][256]
  __bf16* KST  = (__bf16*)take(4194304);
  __bf16* QCT  = (__bf16*)take(4194304);
  __bf16* KCT  = (__bf16*)take(4194304);
  __bf16* VS   = (__bf16*)take(4194304);   // Vs    [b][256][4096]
  __bf16* VC   = (__bf16*)take(4194304);
  __bf16* GTS  = (__bf16*)take(8388608);   // G (reshape layout) [br*2+z][4096][256]
  __bf16* AL   = (__bf16*)take(4718592);   // conv weights [1024][2304]
  __bf16* AV   = (__bf16*)take(2359296);   // [512][2304]
  __bf16* WT   = (__bf16*)take(524288);    // folded tail weights [256][1024]
  float*  BT   = (float*)take(1024);       // folded tail bias [256]
  float*  MST  = (float*)take(65536);      // [br*2+z][4096]
  float*  LST  = (float*)take(65536);
  float*  PM   = (float*)take(131072);     // partial stats [ih][zbr][4096]
  float*  PL   = (float*)take(131072);
  __bf16* Xt   = (__bf16*)take(8388608);   // [img][4096][256] — alive through tail
  size_t ovl = off;                        // overlay: Cc (conv) / GACC (attn)
  __bf16* Cc = (__bf16*)take(75497472);
  size_t needConv = off;
  float* GACC = (float*)(ws + ovl);        // [2 qh][4 zbr][4096*256] fp32 = 32 MB
  size_t needAttn = ovl + 33554432;
  size_t need = needConv > needAttn ? needConv : needAttn;
  if (ws_size < need) return;

  transpose_cvt<<<dim3(128, 8, 4), dim3(32, 8), 0, stream>>>(Fl, Fv, Xt);
  im2col_k<<<dim3(4608, 4), 256, 0, stream>>>(Xt, Cc);
  W6 wp; wp.w[0]=Wqs; wp.w[1]=Wks; wp.w[2]=Wvs; wp.w[3]=Wqc; wp.w[4]=Wkc; wp.w[5]=Wvc;
  repack_w3<<<dim3(2304, 6), 256, 0, stream>>>(wp, AL, AV);
  wcomb<<<dim3(256), 256, 0, stream>>>(Wgs, bgs, Wfu, bfu, WT, BT);

  gemm_conv<<<dim3(32, 12, 2), 256, 0, stream>>>(
      AL, AV, Cc, QST, KST, VS, QCT, KCT, VC,
      bqs, bks, bvs, bqc, bkc, bvc);

  qk_stats<<<dim3(512), 256, 0, stream>>>(QST, QCT, KST, KCT, PM, PL);
  stats_combine2<<<dim3(16, 4), 256, 0, stream>>>(PM, PL, MST, LST);

  fused_pv<<<dim3(512), 256, 0, stream>>>(
      QST, QCT, KST, KCT, VS, VC, MST, LST, GACC);

  gsum_reshape<<<dim3(4, 16, 4), 256, 0, stream>>>(GACC, GTS);

  tail_gemm<<<dim3(32, 2, 2), 256, 0, stream>>>(WT, GTS, Xt, BT, (float*)d_out);
}